// Round 1
// baseline (2635.103 us; speedup 1.0000x reference)
//
#include <hip/hip_runtime.h>
#include <math.h>

#define BB 2
#define NN 32768
#define KK 16
#define CC 64
#define CM 32
#define WNC 16
#define MTOT (BB*NN*KK)   // 1048576

static_assert(MTOT == 1048576, "size");

// ---------------------------------------------------------------------------
// block-wide reduce (blockDim.x == 256) of NV floats, atomicAdd into gdst[NV]
// ---------------------------------------------------------------------------
template<int NV>
__device__ __forceinline__ void block_reduce_atomic(const float* v, float* gdst) {
    __shared__ float red[NV * 4];
    const int lane = threadIdx.x & 63;
    const int wv   = threadIdx.x >> 6;
    float tmp[NV];
#pragma unroll
    for (int i = 0; i < NV; ++i) {
        float x = v[i];
#pragma unroll
        for (int off = 32; off > 0; off >>= 1) x += __shfl_down(x, off, 64);
        tmp[i] = x;
    }
    if (lane == 0) {
#pragma unroll
        for (int i = 0; i < NV; ++i) red[wv * NV + i] = tmp[i];
    }
    __syncthreads();
    if (threadIdx.x < NV) {
        float s = red[threadIdx.x] + red[NV + threadIdx.x] +
                  red[2 * NV + threadIdx.x] + red[3 * NV + threadIdx.x];
        atomicAdd(gdst + threadIdx.x, s);
    }
}

// ---------------------------------------------------------------------------
// Kernel 1: geometry -> wn_in (12) -> z0 = wn_in @ W0^T + b0  (8 ch)
// accumulate sum/sumsq of z0 into stats[0..7]/stats[8..15]
// ---------------------------------------------------------------------------
__global__ __launch_bounds__(256)
void k_geom_l0(const float* __restrict__ xyz, const float* __restrict__ xyzn,
               const int* __restrict__ nei,
               const float* __restrict__ W0, const float* __restrict__ b0,
               float* __restrict__ z0, float* __restrict__ stats) {
    const int t = blockIdx.x * 256 + threadIdx.x;           // < MTOT
    const int b   = t / (NN * KK);
    const int rem = t - b * (NN * KK);
    const int n   = rem >> 4;                                // /KK
    const int j   = nei[t];

    const float* cx = xyz  + ((size_t)b * NN + n) * 3;
    const float* cn = xyzn + ((size_t)b * NN + n) * 3;
    const float* gx = xyz  + ((size_t)b * NN + j) * 3;
    const float* gn = xyzn + ((size_t)b * NN + j) * 3;

    const float rx = gx[0] - cx[0], ry = gx[1] - cx[1], rz = gx[2] - cx[2];
    const float nmx = cn[0], nmy = cn[1], nmz = cn[2];
    const float gnx = gn[0], gny = gn[1], gnz = gn[2];

    const float rlen = sqrtf(rx * rx + ry * ry + rz * rz);
    const float rinv = 1.0f / fmaxf(rlen, 1e-12f);
    const float rhx = rx * rinv, rhy = ry * rinv, rhz = rz * rinv;

    const float d_nr = nmx * rhx + nmy * rhy + nmz * rhz;    // th2
    float vx = nmx - d_nr * rhx, vy = nmy - d_nr * rhy, vz = nmz - d_nr * rhz;
    const float vinv = 1.0f / fmaxf(sqrtf(vx * vx + vy * vy + vz * vz), 1e-12f);
    vx *= vinv; vy *= vinv; vz *= vinv;

    float wx = rhy * vz - rhz * vy;
    float wy = rhz * vx - rhx * vz;
    float wz = rhx * vy - rhy * vx;
    const float winv = 1.0f / fmaxf(sqrtf(wx * wx + wy * wy + wz * wz), 1e-12f);
    wx *= winv; wy *= winv; wz *= winv;

    const float th1 = gnx * nmx + gny * nmy + gnz * nmz;
    const float th3 = rhx * gnx + rhy * gny + rhz * gnz;
    const float th4 = rx * nmx + ry * nmy + rz * nmz;
    const float th6 = gnx * vx + gny * vy + gnz * vz;
    const float th7 = gnx * wx + gny * wy + gnz * wz;
    const float ccx = gny * nmz - gnz * nmy;
    const float ccy = gnz * nmx - gnx * nmz;
    const float ccz = gnx * nmy - gny * nmx;
    const float th8 = rx * ccx + ry * ccy + rz * ccz;

    const float win[12] = {th1, d_nr, th3, th4, th3, th6, th7, th8, rlen, rx, ry, rz};

    float v[16];
#pragma unroll
    for (int o = 0; o < 8; ++o) {
        float acc = b0[o];
#pragma unroll
        for (int c = 0; c < 12; ++c) acc += win[c] * W0[o * 12 + c];
        z0[(size_t)t * 8 + o] = acc;
        v[o] = acc; v[8 + o] = acc * acc;
    }
    block_reduce_atomic<16>(v, stats);
}

// ---------------------------------------------------------------------------
// Kernel 2: BN0(z0) -> relu -> z1 = a @ W1^T + b1 (8 ch); stats1 at +16/+24
// ---------------------------------------------------------------------------
__global__ __launch_bounds__(256)
void k_l1(const float* __restrict__ z0, const float* __restrict__ W1,
          const float* __restrict__ b1, const float* __restrict__ g0,
          const float* __restrict__ be0, float* __restrict__ stats,
          float* __restrict__ z1) {
    const int t = blockIdx.x * 256 + threadIdx.x;
    const float invM = 1.0f / (float)MTOT;
    float a[8];
#pragma unroll
    for (int c = 0; c < 8; ++c) {
        const float mean = stats[c] * invM;
        const float var  = stats[8 + c] * invM - mean * mean;
        const float x = z0[(size_t)t * 8 + c];
        const float y = (x - mean) * rsqrtf(var + 1e-5f) * g0[c] + be0[c];
        a[c] = fmaxf(y, 0.0f);
    }
    float v[16];
#pragma unroll
    for (int o = 0; o < 8; ++o) {
        float acc = b1[o];
#pragma unroll
        for (int c = 0; c < 8; ++c) acc += a[c] * W1[o * 8 + c];
        z1[(size_t)t * 8 + o] = acc;
        v[o] = acc; v[8 + o] = acc * acc;
    }
    block_reduce_atomic<16>(v, stats + 16);
}

// ---------------------------------------------------------------------------
// Kernel 3: BN1(z1) -> relu -> z2 = a @ W2^T + b2 (16 ch); stats2 at +32/+48
// ---------------------------------------------------------------------------
__global__ __launch_bounds__(256)
void k_l2(const float* __restrict__ z1, const float* __restrict__ W2,
          const float* __restrict__ b2, const float* __restrict__ g1,
          const float* __restrict__ be1, float* __restrict__ stats,
          float* __restrict__ z2) {
    const int t = blockIdx.x * 256 + threadIdx.x;
    const float invM = 1.0f / (float)MTOT;
    float a[8];
#pragma unroll
    for (int c = 0; c < 8; ++c) {
        const float mean = stats[16 + c] * invM;
        const float var  = stats[24 + c] * invM - mean * mean;
        const float x = z1[(size_t)t * 8 + c];
        const float y = (x - mean) * rsqrtf(var + 1e-5f) * g1[c] + be1[c];
        a[c] = fmaxf(y, 0.0f);
    }
    float v[32];
#pragma unroll
    for (int o = 0; o < 16; ++o) {
        float acc = b2[o];
#pragma unroll
        for (int c = 0; c < 8; ++c) acc += a[c] * W2[o * 8 + c];
        z2[(size_t)t * 16 + o] = acc;
        v[o] = acc; v[16 + o] = acc * acc;
    }
    block_reduce_atomic<32>(v, stats + 32);
}

// ---------------------------------------------------------------------------
// Kernel 4: per-point block (256 thr): gather feats, h-MLP, w=BN2(z2)->relu,
// agg = h^T w (32x16), out = relu(agg @ W_lin^T + b_lin) + feats
// ---------------------------------------------------------------------------
__global__ __launch_bounds__(256)
void k_final(const float* __restrict__ xyz, const float* __restrict__ feats,
             const int* __restrict__ nei,
             const float* __restrict__ Wm1, const float* __restrict__ bm1,
             const float* __restrict__ Wm2, const float* __restrict__ bm2,
             const float* __restrict__ g2, const float* __restrict__ be2,
             const float* __restrict__ Wlin, const float* __restrict__ blin,
             const float* __restrict__ z2, const float* __restrict__ stats2,
             float* __restrict__ out) {
    const int pn = blockIdx.x;            // 0 .. B*N-1
    const int b  = pn >> 15;              // / NN
    const int t  = threadIdx.x;

    __shared__ int   nidx[KK];
    __shared__ float gfeat[KK][CC];       // 4 KB
    __shared__ float rmiu[KK][3];
    __shared__ float wlds[KK][WNC];       // 1 KB
    __shared__ float h1[KK][CM];          // 2 KB
    __shared__ float h2[KK][CM];          // 2 KB
    __shared__ float agg[CM * WNC];       // 2 KB
    __shared__ float pred[256];           // 1 KB

    if (t < KK) nidx[t] = nei[(size_t)pn * KK + t];
    __syncthreads();

    // gather g_feat as float4 (16 rows x 16 float4)
    {
        const int k  = t >> 4;
        const int c4 = t & 15;
        const float4* src = reinterpret_cast<const float4*>(
            feats + ((size_t)b * NN + nidx[k]) * CC) + c4;
        reinterpret_cast<float4*>(&gfeat[k][0])[c4] = *src;
    }
    if (t < KK * 3) {
        const int k = t / 3, d = t - k * 3;
        rmiu[k][d] = xyz[((size_t)b * NN + nidx[k]) * 3 + d] - xyz[(size_t)pn * 3 + d];
    }
    // w = relu(BN2(z2))
    {
        const int k = t >> 4, jj = t & 15;
        const float invM = 1.0f / (float)MTOT;
        const float mean = stats2[jj] * invM;
        const float var  = stats2[16 + jj] * invM - mean * mean;
        const float x = z2[(size_t)pn * (KK * WNC) + t];
        const float y = (x - mean) * rsqrtf(var + 1e-5f) * g2[jj] + be2[jj];
        wlds[k][jj] = fmaxf(y, 0.0f);
    }
    __syncthreads();

    // h1 = relu([g_feat, r_miu] @ Wm1^T + bm1): 16x32 outputs, 2/thread
#pragma unroll
    for (int it = 0; it < 2; ++it) {
        const int idx = t + it * 256;
        const int k = idx >> 5, o = idx & 31;
        const float* wr = Wm1 + o * 67;
        float acc = bm1[o];
#pragma unroll
        for (int c = 0; c < 64; ++c) acc += gfeat[k][c] * wr[c];
        acc += rmiu[k][0] * wr[64] + rmiu[k][1] * wr[65] + rmiu[k][2] * wr[66];
        h1[k][o] = fmaxf(acc, 0.0f);
    }
    __syncthreads();

    // h2 = relu(h1 @ Wm2^T + bm2)
#pragma unroll
    for (int it = 0; it < 2; ++it) {
        const int idx = t + it * 256;
        const int k = idx >> 5, o = idx & 31;
        const float* wr = Wm2 + o * 32;
        float acc = bm2[o];
#pragma unroll
        for (int c = 0; c < 32; ++c) acc += h1[k][c] * wr[c];
        h2[k][o] = fmaxf(acc, 0.0f);
    }
    __syncthreads();

    // agg[c*16+j] = sum_k h2[k][c] * w[k][j]
#pragma unroll
    for (int it = 0; it < 2; ++it) {
        const int idx = t + it * 256;
        const int c = idx >> 4, jj = idx & 15;
        float acc = 0.0f;
#pragma unroll
        for (int k = 0; k < KK; ++k) acc += h2[k][c] * wlds[k][jj];
        agg[idx] = acc;
    }
    __syncthreads();

    // out[o] = relu(sum_m agg[m]*Wlin[o][m] + blin[o]) + feats[pn][o]
    {
        const int o = t & 63, part = t >> 6;   // part == wave id
        const float4* wl4 = reinterpret_cast<const float4*>(
            Wlin + (size_t)o * 512 + part * 128);
        const float4* ag4 = reinterpret_cast<const float4*>(agg + part * 128);
        float acc = 0.0f;
#pragma unroll
        for (int i = 0; i < 32; ++i) {
            const float4 w4 = wl4[i];
            const float4 a4 = ag4[i];
            acc += w4.x * a4.x + w4.y * a4.y + w4.z * a4.z + w4.w * a4.w;
        }
        pred[t] = acc;
    }
    __syncthreads();
    if (t < 64) {
        const float s = pred[t] + pred[64 + t] + pred[128 + t] + pred[192 + t];
        out[(size_t)pn * CC + t] = fmaxf(s + blin[t], 0.0f) + feats[(size_t)pn * CC + t];
    }
}

// ---------------------------------------------------------------------------
extern "C" void kernel_launch(void* const* d_in, const int* in_sizes, int n_in,
                              void* d_out, int out_size, void* d_ws, size_t ws_size,
                              hipStream_t stream) {
    const float* xyz  = (const float*)d_in[0];
    const float* feats= (const float*)d_in[1];
    const float* xyzn = (const float*)d_in[2];
    const int*   nei  = (const int*)  d_in[3];
    const float* Wm1  = (const float*)d_in[4];
    const float* bm1  = (const float*)d_in[5];
    const float* Wm2  = (const float*)d_in[6];
    const float* bm2  = (const float*)d_in[7];
    const float* W0   = (const float*)d_in[8];
    const float* b0   = (const float*)d_in[9];
    const float* g0   = (const float*)d_in[10];
    const float* be0  = (const float*)d_in[11];
    const float* W1   = (const float*)d_in[12];
    const float* b1   = (const float*)d_in[13];
    const float* g1   = (const float*)d_in[14];
    const float* be1  = (const float*)d_in[15];
    const float* W2   = (const float*)d_in[16];
    const float* b2   = (const float*)d_in[17];
    const float* g2   = (const float*)d_in[18];
    const float* be2  = (const float*)d_in[19];
    const float* Wlin = (const float*)d_in[20];
    const float* blin = (const float*)d_in[21];

    float* out = (float*)d_out;
    float* ws  = (float*)d_ws;

    float* z0    = ws;                          // 8 * MTOT
    float* z1    = ws + (size_t)MTOT * 8;       // 8 * MTOT
    float* z2    = ws + (size_t)MTOT * 16;      // 16 * MTOT
    float* stats = ws + (size_t)MTOT * 32;      // 64 floats

    hipMemsetAsync(stats, 0, 64 * sizeof(float), stream);

    k_geom_l0<<<MTOT / 256, 256, 0, stream>>>(xyz, xyzn, nei, W0, b0, z0, stats);
    k_l1<<<MTOT / 256, 256, 0, stream>>>(z0, W1, b1, g0, be0, stats, z1);
    k_l2<<<MTOT / 256, 256, 0, stream>>>(z1, W2, b2, g1, be1, stats, z2);
    k_final<<<BB * NN, 256, 0, stream>>>(xyz, feats, nei, Wm1, bm1, Wm2, bm2,
                                         g2, be2, Wlin, blin, z2, stats + 32, out);
}

// Round 2
// 488.965 us; speedup vs baseline: 5.3891x; 5.3891x over previous
//
#include <hip/hip_runtime.h>
#include <math.h>

#define BB 2
#define NN 32768
#define KK 16
#define CC 64
#define CM 32
#define WNC 16
#define MTOT (BB*NN*KK)   // 1048576
#define PTS 16            // points per block in fused kernel

static_assert(MTOT == 1048576, "size");

// ---------------------------------------------------------------------------
// block-wide reduce (blockDim.x == 256) of NV floats, atomicAdd into gdst[NV]
// ---------------------------------------------------------------------------
template<int NV>
__device__ __forceinline__ void block_reduce_atomic(const float* v, float* gdst) {
    __shared__ float red[NV * 4];
    const int lane = threadIdx.x & 63;
    const int wv   = threadIdx.x >> 6;
    float tmp[NV];
#pragma unroll
    for (int i = 0; i < NV; ++i) {
        float x = v[i];
#pragma unroll
        for (int off = 32; off > 0; off >>= 1) x += __shfl_down(x, off, 64);
        tmp[i] = x;
    }
    if (lane == 0) {
#pragma unroll
        for (int i = 0; i < NV; ++i) red[wv * NV + i] = tmp[i];
    }
    __syncthreads();
    if (threadIdx.x < NV) {
        float s = red[threadIdx.x] + red[NV + threadIdx.x] +
                  red[2 * NV + threadIdx.x] + red[3 * NV + threadIdx.x];
        atomicAdd(gdst + threadIdx.x, s);
    }
}

// ---------------------------------------------------------------------------
// Kernel 1: geometry -> wn_in (12) -> z0 = wn_in @ W0^T + b0  (8 ch)
// ---------------------------------------------------------------------------
__global__ __launch_bounds__(256)
void k_geom_l0(const float* __restrict__ xyz, const float* __restrict__ xyzn,
               const int* __restrict__ nei,
               const float* __restrict__ W0, const float* __restrict__ b0,
               float* __restrict__ z0, float* __restrict__ stats) {
    const int t = blockIdx.x * 256 + threadIdx.x;           // < MTOT
    const int b   = t / (NN * KK);
    const int rem = t - b * (NN * KK);
    const int n   = rem >> 4;                                // /KK
    const int j   = nei[t];

    const float* cx = xyz  + ((size_t)b * NN + n) * 3;
    const float* cn = xyzn + ((size_t)b * NN + n) * 3;
    const float* gx = xyz  + ((size_t)b * NN + j) * 3;
    const float* gn = xyzn + ((size_t)b * NN + j) * 3;

    const float rx = gx[0] - cx[0], ry = gx[1] - cx[1], rz = gx[2] - cx[2];
    const float nmx = cn[0], nmy = cn[1], nmz = cn[2];
    const float gnx = gn[0], gny = gn[1], gnz = gn[2];

    const float rlen = sqrtf(rx * rx + ry * ry + rz * rz);
    const float rinv = 1.0f / fmaxf(rlen, 1e-12f);
    const float rhx = rx * rinv, rhy = ry * rinv, rhz = rz * rinv;

    const float d_nr = nmx * rhx + nmy * rhy + nmz * rhz;    // th2
    float vx = nmx - d_nr * rhx, vy = nmy - d_nr * rhy, vz = nmz - d_nr * rhz;
    const float vinv = 1.0f / fmaxf(sqrtf(vx * vx + vy * vy + vz * vz), 1e-12f);
    vx *= vinv; vy *= vinv; vz *= vinv;

    float wx = rhy * vz - rhz * vy;
    float wy = rhz * vx - rhx * vz;
    float wz = rhx * vy - rhy * vx;
    const float winv = 1.0f / fmaxf(sqrtf(wx * wx + wy * wy + wz * wz), 1e-12f);
    wx *= winv; wy *= winv; wz *= winv;

    const float th1 = gnx * nmx + gny * nmy + gnz * nmz;
    const float th3 = rhx * gnx + rhy * gny + rhz * gnz;
    const float th4 = rx * nmx + ry * nmy + rz * nmz;
    const float th6 = gnx * vx + gny * vy + gnz * vz;
    const float th7 = gnx * wx + gny * wy + gnz * wz;
    const float ccx = gny * nmz - gnz * nmy;
    const float ccy = gnz * nmx - gnx * nmz;
    const float ccz = gnx * nmy - gny * nmx;
    const float th8 = rx * ccx + ry * ccy + rz * ccz;

    const float win[12] = {th1, d_nr, th3, th4, th3, th6, th7, th8, rlen, rx, ry, rz};

    float v[16];
#pragma unroll
    for (int o = 0; o < 8; ++o) {
        float acc = b0[o];
#pragma unroll
        for (int c = 0; c < 12; ++c) acc += win[c] * W0[o * 12 + c];
        z0[(size_t)t * 8 + o] = acc;
        v[o] = acc; v[8 + o] = acc * acc;
    }
    block_reduce_atomic<16>(v, stats);
}

// ---------------------------------------------------------------------------
// Kernel 2: BN0(z0) -> relu -> z1 (8 ch); stats1 at +16/+24
// ---------------------------------------------------------------------------
__global__ __launch_bounds__(256)
void k_l1(const float* __restrict__ z0, const float* __restrict__ W1,
          const float* __restrict__ b1, const float* __restrict__ g0,
          const float* __restrict__ be0, float* __restrict__ stats,
          float* __restrict__ z1) {
    const int t = blockIdx.x * 256 + threadIdx.x;
    const float invM = 1.0f / (float)MTOT;
    float a[8];
#pragma unroll
    for (int c = 0; c < 8; ++c) {
        const float mean = stats[c] * invM;
        const float var  = stats[8 + c] * invM - mean * mean;
        const float x = z0[(size_t)t * 8 + c];
        const float y = (x - mean) * rsqrtf(var + 1e-5f) * g0[c] + be0[c];
        a[c] = fmaxf(y, 0.0f);
    }
    float v[16];
#pragma unroll
    for (int o = 0; o < 8; ++o) {
        float acc = b1[o];
#pragma unroll
        for (int c = 0; c < 8; ++c) acc += a[c] * W1[o * 8 + c];
        z1[(size_t)t * 8 + o] = acc;
        v[o] = acc; v[8 + o] = acc * acc;
    }
    block_reduce_atomic<16>(v, stats + 16);
}

// ---------------------------------------------------------------------------
// Kernel 3: BN1(z1) -> relu -> z2 (16 ch); stats2 at +32/+48
// ---------------------------------------------------------------------------
__global__ __launch_bounds__(256)
void k_l2(const float* __restrict__ z1, const float* __restrict__ W2,
          const float* __restrict__ b2, const float* __restrict__ g1,
          const float* __restrict__ be1, float* __restrict__ stats,
          float* __restrict__ z2) {
    const int t = blockIdx.x * 256 + threadIdx.x;
    const float invM = 1.0f / (float)MTOT;
    float a[8];
#pragma unroll
    for (int c = 0; c < 8; ++c) {
        const float mean = stats[16 + c] * invM;
        const float var  = stats[24 + c] * invM - mean * mean;
        const float x = z1[(size_t)t * 8 + c];
        const float y = (x - mean) * rsqrtf(var + 1e-5f) * g1[c] + be1[c];
        a[c] = fmaxf(y, 0.0f);
    }
    float v[32];
#pragma unroll
    for (int o = 0; o < 16; ++o) {
        float acc = b2[o];
#pragma unroll
        for (int c = 0; c < 8; ++c) acc += a[c] * W2[o * 8 + c];
        z2[(size_t)t * 16 + o] = acc;
        v[o] = acc; v[16 + o] = acc * acc;
    }
    block_reduce_atomic<32>(v, stats + 32);
}

// ---------------------------------------------------------------------------
// Kernel B (fused): 16 points / 256 threads per block.
// thread t: p = t>>4 (local point), k = t&15 (neighbor / j-index)
// LDS time-multiplexed regions (floats, 13312 total = 52 KB):
//   staging:  wm1L [0..2176) rows of 68 (67 + zero pad)
//             wm2L [2176..3200), bm1 [3200..3232), bm2 [3232..3264)
//             bnsc [3264..3280), bnsh [3280..3296)
//   h2L [c][s]: [0..8192)          (written after sync, over staging)
//   wL  [s][20]: [8192..13312)
//   aggL [p][520]: [0..8320)       (written after agg reads complete)
//   part [(q*64+o)*20 + p]: [8192..13312)
// ---------------------------------------------------------------------------
__global__ __launch_bounds__(256, 3)
void k_fused(const float* __restrict__ xyz, const float* __restrict__ feats,
             const int* __restrict__ nei,
             const float* __restrict__ Wm1, const float* __restrict__ bm1,
             const float* __restrict__ Wm2, const float* __restrict__ bm2,
             const float* __restrict__ g2, const float* __restrict__ be2,
             const float* __restrict__ Wlin, const float* __restrict__ blin,
             const float* __restrict__ z2, const float* __restrict__ stats2,
             float* __restrict__ out) {
    __shared__ __align__(16) float lds[13312];
    const int t  = threadIdx.x;
    const int p  = t >> 4;
    const int k  = t & 15;
    const int pn = blockIdx.x * PTS + p;      // global point
    const int b  = pn >> 15;

    // ---- stage weights / BN coefficients into LDS ----
    for (int i = t; i < 2176; i += 256) {
        const int o = i / 68;
        const int c = i - o * 68;
        lds[i] = (c < 67) ? Wm1[o * 67 + c] : 0.f;
    }
    for (int i = t; i < 1024; i += 256) lds[2176 + i] = Wm2[i];
    if (t < 32) {
        lds[3200 + t] = bm1[t];
    } else if (t >= 64 && t < 96) {
        lds[3232 + (t - 64)] = bm2[t - 64];
    } else if (t >= 128 && t < 144) {
        const int jj = t - 128;
        const float invM = 1.0f / (float)MTOT;
        const float mean = stats2[jj] * invM;
        const float var  = stats2[16 + jj] * invM - mean * mean;
        const float sc   = rsqrtf(var + 1e-5f) * g2[jj];
        lds[3264 + jj] = sc;
        lds[3280 + jj] = be2[jj] - mean * sc;
    }

    // ---- per-sample global loads (no LDS dependency; issue before sync) ----
    const int    s_glob = pn * KK + k;
    const int    nj     = nei[s_glob];
    const float* frow   = feats + ((size_t)b * NN + nj) * CC;
    const float4* frow4 = (const float4*)frow;

    const float cx0 = xyz[(size_t)pn * 3 + 0];
    const float cy0 = xyz[(size_t)pn * 3 + 1];
    const float cz0 = xyz[(size_t)pn * 3 + 2];
    const float* nxp = xyz + ((size_t)b * NN + nj) * 3;
    const float rmx = nxp[0] - cx0, rmy = nxp[1] - cy0, rmz = nxp[2] - cz0;

    const float4* zr = (const float4*)(z2 + (size_t)s_glob * WNC);
    const float4 zv0 = zr[0], zv1 = zr[1], zv2 = zr[2], zv3 = zr[3];

    float4 cur = frow4[0];

    __syncthreads();

    // ---- w = relu(BN2(z2)) (folded scale/shift from LDS) ----
    float wv_[16];
    {
        float zt[16] = {zv0.x, zv0.y, zv0.z, zv0.w, zv1.x, zv1.y, zv1.z, zv1.w,
                        zv2.x, zv2.y, zv2.z, zv2.w, zv3.x, zv3.y, zv3.z, zv3.w};
#pragma unroll
        for (int jj = 0; jj < 16; ++jj)
            wv_[jj] = fmaxf(zt[jj] * lds[3264 + jj] + lds[3280 + jj], 0.f);
    }

    // ---- h1 = relu([gfeat, rmiu] @ Wm1^T + bm1), rolled c4 loop ----
    float acc[32];
#pragma unroll
    for (int o = 0; o < 32; ++o) acc[o] = lds[3200 + o];
#pragma unroll 1
    for (int c4 = 0; c4 < 16; ++c4) {
        float4 nxt = cur;
        if (c4 < 15) nxt = frow4[c4 + 1];
#pragma unroll
        for (int o = 0; o < 32; ++o) {
            const float4 wv = *(const float4*)&lds[o * 68 + c4 * 4];
            acc[o] += cur.x * wv.x + cur.y * wv.y + cur.z * wv.z + cur.w * wv.w;
        }
        cur = nxt;
    }
    float h1v[32];
#pragma unroll
    for (int o = 0; o < 32; ++o) {
        const float4 wv = *(const float4*)&lds[o * 68 + 64];
        acc[o] += rmx * wv.x + rmy * wv.y + rmz * wv.z;
        h1v[o] = fmaxf(acc[o], 0.f);
    }

    // ---- h2 = relu(h1 @ Wm2^T + bm2) ----
    float h2v[32];
#pragma unroll
    for (int o = 0; o < 32; ++o) {
        const float4* wr = (const float4*)&lds[2176 + o * 32];
        float a2 = lds[3232 + o];
#pragma unroll
        for (int c4 = 0; c4 < 8; ++c4) {
            const float4 wv = wr[c4];
            a2 += h1v[c4 * 4 + 0] * wv.x + h1v[c4 * 4 + 1] * wv.y +
                  h1v[c4 * 4 + 2] * wv.z + h1v[c4 * 4 + 3] * wv.w;
        }
        h2v[o] = fmaxf(a2, 0.f);
    }

    __syncthreads();   // staging reads done; safe to overwrite

    // ---- redistribute via LDS: h2L [c][t], wL [t][20] ----
#pragma unroll
    for (int c = 0; c < 32; ++c) lds[c * 256 + t] = h2v[c];
#pragma unroll
    for (int w4 = 0; w4 < 4; ++w4)
        *(float4*)&lds[8192 + t * 20 + w4 * 4] =
            make_float4(wv_[w4 * 4], wv_[w4 * 4 + 1], wv_[w4 * 4 + 2], wv_[w4 * 4 + 3]);

    __syncthreads();

    // ---- agg[p][c][j] = sum_k h2[p,k][c] * w[p,k][j]  (thread = (p, j=k)) ----
    float wk[16];
#pragma unroll
    for (int kk = 0; kk < 16; ++kk) wk[kk] = lds[8192 + (p * 16 + kk) * 20 + k];
    float aggv[32];
#pragma unroll
    for (int c = 0; c < 32; ++c) {
        const float4* hr = (const float4*)&lds[c * 256 + p * 16];
        float a = 0.f;
#pragma unroll
        for (int k4 = 0; k4 < 4; ++k4) {
            const float4 h4 = hr[k4];
            a += h4.x * wk[k4 * 4 + 0] + h4.y * wk[k4 * 4 + 1] +
                 h4.z * wk[k4 * 4 + 2] + h4.w * wk[k4 * 4 + 3];
        }
        aggv[c] = a;
    }

    __syncthreads();   // h2L/wL reads done

    // ---- aggL [p][520] ----
#pragma unroll
    for (int c = 0; c < 32; ++c) lds[p * 520 + c * 16 + k] = aggv[c];

    __syncthreads();

    // ---- final: out[p][o] = relu(agg[p] . Wlin[o] + blin[o]) + feats ----
    // thread owns (o = t&63, K-quarter q = t>>6); 16 point-accumulators
    {
        const int o = t & 63, q = t >> 6;
        float part[16];
#pragma unroll
        for (int pp = 0; pp < 16; ++pp) part[pp] = 0.f;
        const float4* wl4 = (const float4*)(Wlin + (size_t)o * 512 + q * 128);
#pragma unroll 1
        for (int m4 = 0; m4 < 32; ++m4) {
            const float4 wv = wl4[m4];
#pragma unroll
            for (int pp = 0; pp < 16; ++pp) {
                const float4 a4 = *(const float4*)&lds[pp * 520 + q * 128 + m4 * 4];
                part[pp] += a4.x * wv.x + a4.y * wv.y + a4.z * wv.z + a4.w * wv.w;
            }
        }
        __syncthreads();   // aggL reads done before partials overwrite [8192..)
#pragma unroll
        for (int w4 = 0; w4 < 4; ++w4)
            *(float4*)&lds[8192 + (q * 64 + o) * 20 + w4 * 4] =
                make_float4(part[w4 * 4], part[w4 * 4 + 1],
                            part[w4 * 4 + 2], part[w4 * 4 + 3]);
    }

    __syncthreads();

#pragma unroll
    for (int it = 0; it < 4; ++it) {
        const int idx = t + it * 256;
        const int po = idx >> 6, oo = idx & 63;
        float s = lds[8192 + (oo) * 20 + po] +
                  lds[8192 + (64 + oo) * 20 + po] +
                  lds[8192 + (128 + oo) * 20 + po] +
                  lds[8192 + (192 + oo) * 20 + po];
        s = fmaxf(s + blin[oo], 0.f);
        const size_t gp = (size_t)(blockIdx.x * PTS + po);
        out[gp * CC + oo] = s + feats[gp * CC + oo];
    }
}

// ---------------------------------------------------------------------------
extern "C" void kernel_launch(void* const* d_in, const int* in_sizes, int n_in,
                              void* d_out, int out_size, void* d_ws, size_t ws_size,
                              hipStream_t stream) {
    const float* xyz  = (const float*)d_in[0];
    const float* feats= (const float*)d_in[1];
    const float* xyzn = (const float*)d_in[2];
    const int*   nei  = (const int*)  d_in[3];
    const float* Wm1  = (const float*)d_in[4];
    const float* bm1  = (const float*)d_in[5];
    const float* Wm2  = (const float*)d_in[6];
    const float* bm2  = (const float*)d_in[7];
    const float* W0   = (const float*)d_in[8];
    const float* b0   = (const float*)d_in[9];
    const float* g0   = (const float*)d_in[10];
    const float* be0  = (const float*)d_in[11];
    const float* W1   = (const float*)d_in[12];
    const float* b1   = (const float*)d_in[13];
    const float* g1   = (const float*)d_in[14];
    const float* be1  = (const float*)d_in[15];
    const float* W2   = (const float*)d_in[16];
    const float* b2   = (const float*)d_in[17];
    const float* g2   = (const float*)d_in[18];
    const float* be2  = (const float*)d_in[19];
    const float* Wlin = (const float*)d_in[20];
    const float* blin = (const float*)d_in[21];

    float* out = (float*)d_out;
    float* ws  = (float*)d_ws;

    float* z0    = ws;                          // 8 * MTOT
    float* z1    = ws + (size_t)MTOT * 8;       // 8 * MTOT
    float* z2    = ws + (size_t)MTOT * 16;      // 16 * MTOT
    float* stats = ws + (size_t)MTOT * 32;      // 64 floats

    hipMemsetAsync(stats, 0, 64 * sizeof(float), stream);

    k_geom_l0<<<MTOT / 256, 256, 0, stream>>>(xyz, xyzn, nei, W0, b0, z0, stats);
    k_l1<<<MTOT / 256, 256, 0, stream>>>(z0, W1, b1, g0, be0, stats, z1);
    k_l2<<<MTOT / 256, 256, 0, stream>>>(z1, W2, b2, g1, be1, stats, z2);
    k_fused<<<(BB * NN) / PTS, 256, 0, stream>>>(xyz, feats, nei, Wm1, bm1,
                                                 Wm2, bm2, g2, be2, Wlin, blin,
                                                 z2, stats + 32, out);
}

// Round 3
// 181.743 us; speedup vs baseline: 14.4990x; 2.6904x over previous
//
#include <hip/hip_runtime.h>
#include <math.h>

#define BB 2
#define NN 32768
#define KK 16
#define CC 64
#define CM 32
#define WNC 16
#define MTOT (BB*NN*KK)   // 1048576

typedef short short8 __attribute__((ext_vector_type(8)));
typedef float f32x4 __attribute__((ext_vector_type(4)));

static_assert(MTOT == 1048576, "size");

__device__ __forceinline__ short f2bf(float f) {
    union { float f; unsigned u; } c; c.f = f;
    const unsigned r = c.u + 0x7FFFu + ((c.u >> 16) & 1u);   // RNE
    return (short)(r >> 16);
}

__device__ __forceinline__ f32x4 mfma16(short8 a, short8 b, f32x4 c) {
    return __builtin_amdgcn_mfma_f32_16x16x32_bf16(a, b, c, 0, 0, 0);
}

// ---------------------------------------------------------------------------
// shared helpers
// ---------------------------------------------------------------------------
__device__ __forceinline__ void geom12(int s, const float* __restrict__ xyz,
                                       const float* __restrict__ xyzn,
                                       const int* __restrict__ nei, float* win) {
    const int pn = s >> 4;
    const int b  = pn >> 15;
    const int nj = nei[s];
    const size_t gj = (size_t)(b * NN + nj);

    const float cx = xyz[(size_t)pn*3],  cy = xyz[(size_t)pn*3+1],  cz = xyz[(size_t)pn*3+2];
    const float nmx = xyzn[(size_t)pn*3], nmy = xyzn[(size_t)pn*3+1], nmz = xyzn[(size_t)pn*3+2];
    const float gx = xyz[gj*3],  gy = xyz[gj*3+1],  gz = xyz[gj*3+2];
    const float gnx = xyzn[gj*3], gny = xyzn[gj*3+1], gnz = xyzn[gj*3+2];

    const float rx = gx - cx, ry = gy - cy, rz = gz - cz;
    const float rlen = sqrtf(rx*rx + ry*ry + rz*rz);
    const float rinv = 1.0f / fmaxf(rlen, 1e-12f);
    const float rhx = rx*rinv, rhy = ry*rinv, rhz = rz*rinv;

    const float d_nr = nmx*rhx + nmy*rhy + nmz*rhz;
    float vx = nmx - d_nr*rhx, vy = nmy - d_nr*rhy, vz = nmz - d_nr*rhz;
    const float vinv = 1.0f / fmaxf(sqrtf(vx*vx + vy*vy + vz*vz), 1e-12f);
    vx *= vinv; vy *= vinv; vz *= vinv;

    float wx = rhy*vz - rhz*vy;
    float wy = rhz*vx - rhx*vz;
    float wz = rhx*vy - rhy*vx;
    const float winv = 1.0f / fmaxf(sqrtf(wx*wx + wy*wy + wz*wz), 1e-12f);
    wx *= winv; wy *= winv; wz *= winv;

    const float th1 = gnx*nmx + gny*nmy + gnz*nmz;
    const float th3 = rhx*gnx + rhy*gny + rhz*gnz;
    const float th4 = rx*nmx + ry*nmy + rz*nmz;
    const float th6 = gnx*vx + gny*vy + gnz*vz;
    const float th7 = gnx*wx + gny*wy + gnz*wz;
    const float ccx = gny*nmz - gnz*nmy;
    const float ccy = gnz*nmx - gnx*nmz;
    const float ccz = gnx*nmy - gny*nmx;
    const float th8 = rx*ccx + ry*ccy + rz*ccz;

    win[0]=th1; win[1]=d_nr; win[2]=th3; win[3]=th4; win[4]=th3; win[5]=th6;
    win[6]=th7; win[7]=th8; win[8]=rlen; win[9]=rx; win[10]=ry; win[11]=rz;
}

template<int ON, int IN>
__device__ __forceinline__ void lin(const float* a, const float* __restrict__ W,
                                    const float* __restrict__ bias, float* z) {
#pragma unroll
    for (int o = 0; o < ON; ++o) {
        float acc = bias[o];
#pragma unroll
        for (int c = 0; c < IN; ++c) acc += a[c] * W[o*IN + c];
        z[o] = acc;
    }
}

template<int NCH>
__device__ __forceinline__ void bnrelu(const float* z, const float* __restrict__ st,
                                       const float* __restrict__ g,
                                       const float* __restrict__ be, float* a) {
    const float invM = 1.0f / (float)MTOT;
#pragma unroll
    for (int c = 0; c < NCH; ++c) {
        const float m = st[c] * invM;
        const float v = st[NCH + c] * invM - m*m;
        a[c] = fmaxf((z[c] - m) * rsqrtf(v + 1e-5f) * g[c] + be[c], 0.0f);
    }
}

template<int NV>
__device__ __forceinline__ void block_reduce_atomic(const float* v, float* gdst) {
    __shared__ float red[NV * 4];
    const int lane = threadIdx.x & 63;
    const int wv   = threadIdx.x >> 6;
    float tmp[NV];
#pragma unroll
    for (int i = 0; i < NV; ++i) {
        float x = v[i];
#pragma unroll
        for (int off = 32; off > 0; off >>= 1) x += __shfl_down(x, off, 64);
        tmp[i] = x;
    }
    if (lane == 0) {
#pragma unroll
        for (int i = 0; i < NV; ++i) red[wv * NV + i] = tmp[i];
    }
    __syncthreads();
    if (threadIdx.x < NV) {
        float s = red[threadIdx.x] + red[NV + threadIdx.x] +
                  red[2*NV + threadIdx.x] + red[3*NV + threadIdx.x];
        atomicAdd(gdst + threadIdx.x, s);
    }
}

// ---------------------------------------------------------------------------
// prep: fragment Wm1 / Wm2 / Wlin into MFMA-B lane order (bf16)
// B-frag (16x16x32): elem j of lane l = B[k = ks*32+(l>>4)*8+j][n = nt*16+(l&15)]
// ---------------------------------------------------------------------------
__global__ void k_prep(const float* __restrict__ Wm1, const float* __restrict__ Wm2,
                       const float* __restrict__ Wlin,
                       short* __restrict__ fWm1, short* __restrict__ fWm2,
                       short* __restrict__ fWlin) {
    const int gid  = blockIdx.x * 256 + threadIdx.x;
    const int gstr = gridDim.x * 256;
    for (int i = gid; i < 3072; i += gstr) {          // Wm1^T [96pad x 32]
        const int j = i & 7, l = (i >> 3) & 63, fn = i >> 9;   // fn = ks*2+nt
        const int ks = fn >> 1, nt = fn & 1;
        const int k = ks*32 + ((l >> 4) * 8) + j, n = nt*16 + (l & 15);
        fWm1[i] = (k < 67) ? f2bf(Wm1[n*67 + k]) : (short)0;
    }
    for (int i = gid; i < 1024; i += gstr) {          // Wm2^T [32 x 32]
        const int j = i & 7, l = (i >> 3) & 63, nt = i >> 9;
        const int k = ((l >> 4) * 8) + j, n = nt*16 + (l & 15);
        fWm2[i] = f2bf(Wm2[n*32 + k]);
    }
    for (int i = gid; i < 32768; i += gstr) {         // Wlin^T [512 x 64]
        const int j = i & 7, l = (i >> 3) & 63, fn = i >> 9;   // fn = ks*4+nt
        const int ks = fn >> 2, nt = fn & 3;
        const int k = ks*32 + ((l >> 4) * 8) + j, n = nt*16 + (l & 15);
        fWlin[i] = f2bf(Wlin[n*512 + k]);
    }
}

// ---------------------------------------------------------------------------
// stats kernels: grid 512 x 256, 8 samples/thread, register accumulation
// ---------------------------------------------------------------------------
__global__ __launch_bounds__(256)
void kA(const float* __restrict__ xyz, const float* __restrict__ xyzn,
        const int* __restrict__ nei, const float* __restrict__ W0,
        const float* __restrict__ b0, float* __restrict__ stats) {
    const int t = threadIdx.x;
    float acc[16];
#pragma unroll
    for (int i = 0; i < 16; ++i) acc[i] = 0.f;
#pragma unroll 1
    for (int i = 0; i < 8; ++i) {
        const int s = blockIdx.x*2048 + i*256 + t;
        float win[12]; geom12(s, xyz, xyzn, nei, win);
        float z0[8];  lin<8,12>(win, W0, b0, z0);
#pragma unroll
        for (int o = 0; o < 8; ++o) { acc[o] += z0[o]; acc[8+o] += z0[o]*z0[o]; }
    }
    block_reduce_atomic<16>(acc, stats);
}

__global__ __launch_bounds__(256)
void kB(const float* __restrict__ xyz, const float* __restrict__ xyzn,
        const int* __restrict__ nei, const float* __restrict__ W0,
        const float* __restrict__ b0, const float* __restrict__ g0,
        const float* __restrict__ be0, const float* __restrict__ W1,
        const float* __restrict__ b1, float* __restrict__ stats) {
    const int t = threadIdx.x;
    float acc[16];
#pragma unroll
    for (int i = 0; i < 16; ++i) acc[i] = 0.f;
#pragma unroll 1
    for (int i = 0; i < 8; ++i) {
        const int s = blockIdx.x*2048 + i*256 + t;
        float win[12]; geom12(s, xyz, xyzn, nei, win);
        float z0[8];  lin<8,12>(win, W0, b0, z0);
        float a0[8];  bnrelu<8>(z0, stats, g0, be0, a0);
        float z1[8];  lin<8,8>(a0, W1, b1, z1);
#pragma unroll
        for (int o = 0; o < 8; ++o) { acc[o] += z1[o]; acc[8+o] += z1[o]*z1[o]; }
    }
    block_reduce_atomic<16>(acc, stats + 16);
}

__global__ __launch_bounds__(256)
void kC(const float* __restrict__ xyz, const float* __restrict__ xyzn,
        const int* __restrict__ nei, const float* __restrict__ W0,
        const float* __restrict__ b0, const float* __restrict__ g0,
        const float* __restrict__ be0, const float* __restrict__ W1,
        const float* __restrict__ b1, const float* __restrict__ g1,
        const float* __restrict__ be1, const float* __restrict__ W2,
        const float* __restrict__ b2, float* __restrict__ stats) {
    const int t = threadIdx.x;
    float acc[32];
#pragma unroll
    for (int i = 0; i < 32; ++i) acc[i] = 0.f;
#pragma unroll 1
    for (int i = 0; i < 8; ++i) {
        const int s = blockIdx.x*2048 + i*256 + t;
        float win[12]; geom12(s, xyz, xyzn, nei, win);
        float z0[8];  lin<8,12>(win, W0, b0, z0);
        float a0[8];  bnrelu<8>(z0, stats, g0, be0, a0);
        float z1[8];  lin<8,8>(a0, W1, b1, z1);
        float a1[8];  bnrelu<8>(z1, stats + 16, g1, be1, a1);
        float z2[16]; lin<16,8>(a1, W2, b2, z2);
#pragma unroll
        for (int o = 0; o < 16; ++o) { acc[o] += z2[o]; acc[16+o] += z2[o]*z2[o]; }
    }
    block_reduce_atomic<32>(acc, stats + 32);
}

// ---------------------------------------------------------------------------
// k_fused: 16 points (256 samples) per block, 4 waves, MFMA everywhere.
// LDS (bytes): h1buf [256][40bf16] @0 (20480)  -> overlaid by aggL [16][520bf16]
//              h2T [32][264bf16] @20480 (16896)
//              wBT [16p][16j][16k bf16 +pad] @37376 (16*544=8704)   total 46080
// ---------------------------------------------------------------------------
__global__ __launch_bounds__(256, 3)
void k_fused(const float* __restrict__ xyz, const float* __restrict__ xyzn,
             const float* __restrict__ feats, const int* __restrict__ nei,
             const float* __restrict__ W0, const float* __restrict__ b0,
             const float* __restrict__ g0, const float* __restrict__ be0,
             const float* __restrict__ W1, const float* __restrict__ b1,
             const float* __restrict__ g1, const float* __restrict__ be1,
             const float* __restrict__ W2, const float* __restrict__ b2,
             const float* __restrict__ g2, const float* __restrict__ be2,
             const float* __restrict__ bm1, const float* __restrict__ bm2,
             const float* __restrict__ blin, const float* __restrict__ stats,
             const short* __restrict__ fWm1, const short* __restrict__ fWm2,
             const short* __restrict__ fWlin, float* __restrict__ out) {
    __shared__ __align__(16) unsigned char smem[46080];
    const int t    = threadIdx.x;
    const int lane = t & 63;
    const int wv   = t >> 6;
    const int blk  = blockIdx.x;
    const int sbase = blk * 256;
    const int b     = (blk >= 2048) ? 1 : 0;
    const int lrow  = lane & 15;
    const int kq    = lane >> 4;

    // ---- P0: per-thread wn chain -> w -> wBT (bf16 [p][j][k]) ----
    {
        const int s = sbase + t;
        float win[12]; geom12(s, xyz, xyzn, nei, win);
        float z0[8];  lin<8,12>(win, W0, b0, z0);
        float a0[8];  bnrelu<8>(z0, stats, g0, be0, a0);
        float z1[8];  lin<8,8>(a0, W1, b1, z1);
        float a1[8];  bnrelu<8>(z1, stats + 16, g1, be1, a1);
        float z2[16]; lin<16,8>(a1, W2, b2, z2);
        float w[16];  bnrelu<16>(z2, stats + 32, g2, be2, w);
        const int p = t >> 4, kk = t & 15;
        unsigned short* WBT = (unsigned short*)(smem + 37376);
#pragma unroll
        for (int j = 0; j < 16; ++j)
            WBT[p*272 + j*16 + kk] = (unsigned short)f2bf(w[j]);
    }
    // no barrier: wBT is consumed by the same wave (P3)

    // ---- P1: h1 = relu([gfeat,rmiu] @ Wm1^T + bm1)  (MFMA, A from global) ----
    {
        short8 bW[3][2];
#pragma unroll
        for (int ks = 0; ks < 3; ++ks)
#pragma unroll
            for (int nt = 0; nt < 2; ++nt)
                bW[ks][nt] = *(const short8*)(fWm1 + ((ks*2 + nt)*64 + lane)*8);

        f32x4 C1[4][2];
#pragma unroll
        for (int mt = 0; mt < 4; ++mt)
#pragma unroll
            for (int nt = 0; nt < 2; ++nt)
                C1[mt][nt] = (f32x4){0.f, 0.f, 0.f, 0.f};

#pragma unroll
        for (int mt = 0; mt < 4; ++mt) {
            const int r  = wv*64 + mt*16 + lrow;       // local sample row
            const int sg = sbase + r;
            const int nj = nei[sg];
            const float* F = feats + ((size_t)(b*NN + nj)) * CC;
#pragma unroll
            for (int ks = 0; ks < 2; ++ks) {
                const int kb = ks*32 + kq*8;
                const float4 f0 = *(const float4*)(F + kb);
                const float4 f1 = *(const float4*)(F + kb + 4);
                short8 a;
                a[0]=f2bf(f0.x); a[1]=f2bf(f0.y); a[2]=f2bf(f0.z); a[3]=f2bf(f0.w);
                a[4]=f2bf(f1.x); a[5]=f2bf(f1.y); a[6]=f2bf(f1.z); a[7]=f2bf(f1.w);
                C1[mt][0] = mfma16(a, bW[ks][0], C1[mt][0]);
                C1[mt][1] = mfma16(a, bW[ks][1], C1[mt][1]);
            }
            {   // ks = 2: rmiu channels 64..66, rest zero
                short8 a = (short8){0,0,0,0,0,0,0,0};
                if (kq == 0) {
                    const int pnr = sg >> 4;
                    const float* cp = xyz + (size_t)pnr*3;
                    const float* gp = xyz + ((size_t)(b*NN + nj))*3;
                    a[0] = f2bf(gp[0]-cp[0]);
                    a[1] = f2bf(gp[1]-cp[1]);
                    a[2] = f2bf(gp[2]-cp[2]);
                }
                C1[mt][0] = mfma16(a, bW[2][0], C1[mt][0]);
                C1[mt][1] = mfma16(a, bW[2][1], C1[mt][1]);
            }
        }
        // bias + relu -> h1buf [s][40bf16]
        unsigned short* H1 = (unsigned short*)smem;
#pragma unroll
        for (int mt = 0; mt < 4; ++mt)
#pragma unroll
            for (int nt = 0; nt < 2; ++nt) {
                const int c = nt*16 + lrow;
                const float bias = bm1[c];
#pragma unroll
                for (int reg = 0; reg < 4; ++reg) {
                    const int s = wv*64 + mt*16 + kq*4 + reg;
                    H1[s*40 + c] = (unsigned short)f2bf(fmaxf(C1[mt][nt][reg] + bias, 0.f));
                }
            }
    }

    // ---- P2: h2 = relu(h1 @ Wm2^T + bm2) ----
    {
        short8 bW[2];
        bW[0] = *(const short8*)(fWm2 + (0*64 + lane)*8);
        bW[1] = *(const short8*)(fWm2 + (1*64 + lane)*8);
        const unsigned short* H1 = (const unsigned short*)smem;
        f32x4 C2[4][2];
#pragma unroll
        for (int mt = 0; mt < 4; ++mt)
#pragma unroll
            for (int nt = 0; nt < 2; ++nt)
                C2[mt][nt] = (f32x4){0.f, 0.f, 0.f, 0.f};
#pragma unroll
        for (int mt = 0; mt < 4; ++mt) {
            const int s  = wv*64 + mt*16 + lrow;
            const int c0 = kq*8;
            short8 a = *(const short8*)(H1 + s*40 + c0);
            C2[mt][0] = mfma16(a, bW[0], C2[mt][0]);
            C2[mt][1] = mfma16(a, bW[1], C2[mt][1]);
        }
        // bias + relu -> h2T [c][264bf16]
        unsigned short* H2T = (unsigned short*)(smem + 20480);
#pragma unroll
        for (int mt = 0; mt < 4; ++mt)
#pragma unroll
            for (int nt = 0; nt < 2; ++nt) {
                const int c = nt*16 + lrow;
                const float bias = bm2[c];
#pragma unroll
                for (int reg = 0; reg < 4; ++reg) {
                    const int s = wv*64 + mt*16 + kq*4 + reg;
                    H2T[c*264 + s] = (unsigned short)f2bf(fmaxf(C2[mt][nt][reg] + bias, 0.f));
                }
            }
    }

    __syncthreads();   // all h1buf reads done before aggL overlays region 0

    // ---- P3: agg[p] = h2_p^T (32xK16pad32) @ w_p (K x 16)  -> aggL bf16 ----
    {
        const unsigned short* H2T = (const unsigned short*)(smem + 20480);
        const unsigned char*  WBTb = smem + 37376;
        unsigned short* AGG = (unsigned short*)smem;       // overlay h1buf
#pragma unroll
        for (int pi = 0; pi < 4; ++pi) {
            const int p = wv*4 + pi;
            short8 bf = (short8){0,0,0,0,0,0,0,0};
            if (kq < 2)
                bf = *(const short8*)(WBTb + p*544 + lrow*32 + kq*16);
#pragma unroll
            for (int ct = 0; ct < 2; ++ct) {
                short8 af = (short8){0,0,0,0,0,0,0,0};
                if (kq < 2) {
                    const int c = ct*16 + lrow;
                    af = *(const short8*)(H2T + c*264 + p*16 + kq*8);
                }
                f32x4 Cg = (f32x4){0.f, 0.f, 0.f, 0.f};
                Cg = mfma16(af, bf, Cg);
#pragma unroll
                for (int reg = 0; reg < 4; ++reg) {
                    const int c = ct*16 + kq*4 + reg;
                    AGG[p*520 + c*16 + lrow] = (unsigned short)f2bf(Cg[reg]);
                }
            }
        }
    }

    __syncthreads();   // aggL complete

    // ---- P4: out = relu(agg @ Wlin^T + blin) + feats   (wave = Ntile) ----
    {
        const unsigned short* AGG = (const unsigned short*)smem;
        const int nt = wv;
        f32x4 Co = (f32x4){0.f, 0.f, 0.f, 0.f};
#pragma unroll
        for (int ks = 0; ks < 16; ++ks) {
            const int m0 = ks*32 + kq*8;
            short8 a  = *(const short8*)(AGG + lrow*520 + m0);
            short8 bf = *(const short8*)(fWlin + ((ks*4 + nt)*64 + lane)*8);
            Co = mfma16(a, bf, Co);
        }
        const int o = nt*16 + lrow;
        const float bias = blin[o];
#pragma unroll
        for (int reg = 0; reg < 4; ++reg) {
            const int p = kq*4 + reg;
            const size_t gp = (size_t)blk*16 + p;
            out[gp*CC + o] = fmaxf(Co[reg] + bias, 0.f) + feats[gp*CC + o];
        }
    }
}

// ---------------------------------------------------------------------------
extern "C" void kernel_launch(void* const* d_in, const int* in_sizes, int n_in,
                              void* d_out, int out_size, void* d_ws, size_t ws_size,
                              hipStream_t stream) {
    const float* xyz  = (const float*)d_in[0];
    const float* feats= (const float*)d_in[1];
    const float* xyzn = (const float*)d_in[2];
    const int*   nei  = (const int*)  d_in[3];
    const float* Wm1  = (const float*)d_in[4];
    const float* bm1  = (const float*)d_in[5];
    const float* Wm2  = (const float*)d_in[6];
    const float* bm2  = (const float*)d_in[7];
    const float* W0   = (const float*)d_in[8];
    const float* b0   = (const float*)d_in[9];
    const float* g0   = (const float*)d_in[10];
    const float* be0  = (const float*)d_in[11];
    const float* W1   = (const float*)d_in[12];
    const float* b1   = (const float*)d_in[13];
    const float* g1   = (const float*)d_in[14];
    const float* be1  = (const float*)d_in[15];
    const float* W2   = (const float*)d_in[16];
    const float* b2   = (const float*)d_in[17];
    const float* g2   = (const float*)d_in[18];
    const float* be2  = (const float*)d_in[19];
    const float* Wlin = (const float*)d_in[20];
    const float* blin = (const float*)d_in[21];

    float* out = (float*)d_out;
    char*  ws  = (char*)d_ws;

    float* stats = (float*)ws;                 // 64 f32 @ 0      (256 B)
    short* fWm1  = (short*)(ws + 256);         // 3072  bf16      (6144 B)
    short* fWm2  = (short*)(ws + 6400);        // 1024  bf16      (2048 B)
    short* fWlin = (short*)(ws + 8448);        // 32768 bf16      (65536 B)

    hipMemsetAsync(stats, 0, 256, stream);

    k_prep<<<16, 256, 0, stream>>>(Wm1, Wm2, Wlin, fWm1, fWm2, fWlin);
    kA<<<512, 256, 0, stream>>>(xyz, xyzn, nei, W0, b0, stats);
    kB<<<512, 256, 0, stream>>>(xyz, xyzn, nei, W0, b0, g0, be0, W1, b1, stats);
    kC<<<512, 256, 0, stream>>>(xyz, xyzn, nei, W0, b0, g0, be0, W1, b1,
                                g1, be1, W2, b2, stats);
    k_fused<<<4096, 256, 0, stream>>>(xyz, xyzn, feats, nei,
                                      W0, b0, g0, be0, W1, b1, g1, be1,
                                      W2, b2, g2, be2, bm1, bm2, blin,
                                      stats, fWm1, fWm2, fWlin, out);
}

// Round 4
// 135.551 us; speedup vs baseline: 19.4400x; 1.3408x over previous
//
#include <hip/hip_runtime.h>
#include <math.h>

#define BB 2
#define NN 32768
#define KK 16
#define CC 64
#define CM 32
#define WNC 16
#define MTOT (BB*NN*KK)   // 1048576

typedef short short8 __attribute__((ext_vector_type(8)));
typedef float f32x4 __attribute__((ext_vector_type(4)));

static_assert(MTOT == 1048576, "size");

__device__ __forceinline__ float frsq(float x) { return __builtin_amdgcn_rsqf(x); }

__device__ __forceinline__ unsigned cvtpk(float lo, float hi) {
    unsigned r;
    asm("v_cvt_pk_bf16_f32 %0, %1, %2" : "=v"(r) : "v"(lo), "v"(hi));
    return r;
}

__device__ __forceinline__ short f2bf(float f) {
    union { float f; unsigned u; } c; c.f = f;
    const unsigned r = c.u + 0x7FFFu + ((c.u >> 16) & 1u);   // RNE
    return (short)(r >> 16);
}

__device__ __forceinline__ float bf2f(unsigned short u) {
    union { unsigned u; float f; } c; c.u = ((unsigned)u) << 16; return c.f;
}

__device__ __forceinline__ f32x4 mfma16(short8 a, short8 b, f32x4 c) {
    return __builtin_amdgcn_mfma_f32_16x16x32_bf16(a, b, c, 0, 0, 0);
}

// ---------------------------------------------------------------------------
// geometry -> 12 wn features (fast-math normalizations)
// ---------------------------------------------------------------------------
__device__ __forceinline__ void geom12(int s, const float* __restrict__ xyz,
                                       const float* __restrict__ xyzn,
                                       const int* __restrict__ nei, float* win) {
    const int pn = s >> 4;
    const int b  = pn >> 15;
    const int nj = nei[s];
    const size_t gj = (size_t)(b * NN + nj);

    const float cx = xyz[(size_t)pn*3],  cy = xyz[(size_t)pn*3+1],  cz = xyz[(size_t)pn*3+2];
    const float nmx = xyzn[(size_t)pn*3], nmy = xyzn[(size_t)pn*3+1], nmz = xyzn[(size_t)pn*3+2];
    const float gx = xyz[gj*3],  gy = xyz[gj*3+1],  gz = xyz[gj*3+2];
    const float gnx = xyzn[gj*3], gny = xyzn[gj*3+1], gnz = xyzn[gj*3+2];

    const float rx = gx - cx, ry = gy - cy, rz = gz - cz;
    const float ss = rx*rx + ry*ry + rz*rz;
    const float rinv = frsq(fmaxf(ss, 1e-24f));
    const float rlen = ss * rinv;                       // sqrt(ss)
    const float rhx = rx*rinv, rhy = ry*rinv, rhz = rz*rinv;

    const float d_nr = nmx*rhx + nmy*rhy + nmz*rhz;
    float vx = nmx - d_nr*rhx, vy = nmy - d_nr*rhy, vz = nmz - d_nr*rhz;
    const float vinv = frsq(fmaxf(vx*vx + vy*vy + vz*vz, 1e-24f));
    vx *= vinv; vy *= vinv; vz *= vinv;

    float wx = rhy*vz - rhz*vy;
    float wy = rhz*vx - rhx*vz;
    float wz = rhx*vy - rhy*vx;
    const float winv = frsq(fmaxf(wx*wx + wy*wy + wz*wz, 1e-24f));
    wx *= winv; wy *= winv; wz *= winv;

    const float th1 = gnx*nmx + gny*nmy + gnz*nmz;
    const float th3 = rhx*gnx + rhy*gny + rhz*gnz;
    const float th4 = rx*nmx + ry*nmy + rz*nmz;
    const float th6 = gnx*vx + gny*vy + gnz*vz;
    const float th7 = gnx*wx + gny*wy + gnz*wz;
    const float ccx = gny*nmz - gnz*nmy;
    const float ccy = gnz*nmx - gnx*nmz;
    const float ccz = gnx*nmy - gny*nmx;
    const float th8 = rx*ccx + ry*ccy + rz*ccz;

    win[0]=th1; win[1]=d_nr; win[2]=th3; win[3]=th4; win[4]=th3; win[5]=th6;
    win[6]=th7; win[7]=th8; win[8]=rlen; win[9]=rx; win[10]=ry; win[11]=rz;
}

template<int ON, int IN>
__device__ __forceinline__ void lin(const float* a, const float* __restrict__ W,
                                    const float* __restrict__ bias, float* z) {
#pragma unroll
    for (int o = 0; o < ON; ++o) {
        float acc = bias[o];
#pragma unroll
        for (int c = 0; c < IN; ++c) acc += a[c] * W[o*IN + c];
        z[o] = acc;
    }
}

template<int NCH>
__device__ __forceinline__ void bnrelu(const float* z, const float* __restrict__ st,
                                       const float* __restrict__ g,
                                       const float* __restrict__ be, float* a) {
    const float invM = 1.0f / (float)MTOT;
#pragma unroll
    for (int c = 0; c < NCH; ++c) {
        const float m = st[c] * invM;
        const float v = st[NCH + c] * invM - m*m;
        a[c] = fmaxf((z[c] - m) * frsq(v + 1e-5f) * g[c] + be[c], 0.0f);
    }
}

template<int NV>
__device__ __forceinline__ void block_reduce_atomic(const float* v, float* gdst) {
    __shared__ float red[NV * 4];
    const int lane = threadIdx.x & 63;
    const int wv   = threadIdx.x >> 6;
    float tmp[NV];
#pragma unroll
    for (int i = 0; i < NV; ++i) {
        float x = v[i];
#pragma unroll
        for (int off = 32; off > 0; off >>= 1) x += __shfl_down(x, off, 64);
        tmp[i] = x;
    }
    if (lane == 0) {
#pragma unroll
        for (int i = 0; i < NV; ++i) red[wv * NV + i] = tmp[i];
    }
    __syncthreads();
    if (threadIdx.x < NV) {
        float s = red[threadIdx.x] + red[NV + threadIdx.x] +
                  red[2*NV + threadIdx.x] + red[3*NV + threadIdx.x];
        atomicAdd(gdst + threadIdx.x, s);
    }
}

// ---------------------------------------------------------------------------
// prep: weight fragments (MFMA-B lane order, bf16) + feats f32->bf16
// B-frag (16x16x32): elem j of lane l = B[k = ks*32+(l>>4)*8+j][n = nt*16+(l&15)]
// ---------------------------------------------------------------------------
__global__ __launch_bounds__(256)
void k_prep(const float* __restrict__ Wm1, const float* __restrict__ Wm2,
            const float* __restrict__ Wlin, const float* __restrict__ feats,
            short* __restrict__ fWm1, short* __restrict__ fWm2,
            short* __restrict__ fWlin, unsigned short* __restrict__ featsbf) {
    const int gid  = blockIdx.x * 256 + threadIdx.x;
    const int gstr = gridDim.x * 256;
    for (int i = gid; i < 3072; i += gstr) {          // Wm1^T [96pad x 32]
        const int j = i & 7, l = (i >> 3) & 63, fn = i >> 9;
        const int ks = fn >> 1, nt = fn & 1;
        const int k = ks*32 + ((l >> 4) * 8) + j, n = nt*16 + (l & 15);
        fWm1[i] = (k < 67) ? f2bf(Wm1[n*67 + k]) : (short)0;
    }
    for (int i = gid; i < 1024; i += gstr) {          // Wm2^T [32 x 32]
        const int j = i & 7, l = (i >> 3) & 63, nt = i >> 9;
        const int k = ((l >> 4) * 8) + j, n = nt*16 + (l & 15);
        fWm2[i] = f2bf(Wm2[n*32 + k]);
    }
    for (int i = gid; i < 32768; i += gstr) {         // Wlin^T [512 x 64]
        const int j = i & 7, l = (i >> 3) & 63, fn = i >> 9;
        const int ks = fn >> 2, nt = fn & 3;
        const int k = ks*32 + ((l >> 4) * 8) + j, n = nt*16 + (l & 15);
        fWlin[i] = f2bf(Wlin[n*512 + k]);
    }
    for (int i = gid; i < (BB*NN*CC)/4; i += gstr) {  // feats -> bf16
        const float4 f = *(const float4*)(feats + (size_t)i*4);
        uint2 p; p.x = cvtpk(f.x, f.y); p.y = cvtpk(f.z, f.w);
        *(uint2*)(featsbf + (size_t)i*4) = p;
    }
}

// ---------------------------------------------------------------------------
// kA: geom -> z0 (8ch); store z0 bf16 + rmiu-frag bf16; stats0 @ 0/8
// ---------------------------------------------------------------------------
__global__ __launch_bounds__(256)
void kA(const float* __restrict__ xyz, const float* __restrict__ xyzn,
        const int* __restrict__ nei, const float* __restrict__ W0,
        const float* __restrict__ b0, unsigned short* __restrict__ z0ws,
        unsigned short* __restrict__ rmws, float* __restrict__ stats) {
    const int t = threadIdx.x;
    float acc[16];
#pragma unroll
    for (int i = 0; i < 16; ++i) acc[i] = 0.f;
#pragma unroll
    for (int i = 0; i < 4; ++i) {
        const int s = blockIdx.x*1024 + i*256 + t;
        float win[12]; geom12(s, xyz, xyzn, nei, win);
        float z0[8];  lin<8,12>(win, W0, b0, z0);
        uint4 zp;
        zp.x = cvtpk(z0[0], z0[1]); zp.y = cvtpk(z0[2], z0[3]);
        zp.z = cvtpk(z0[4], z0[5]); zp.w = cvtpk(z0[6], z0[7]);
        *(uint4*)(z0ws + (size_t)s*8) = zp;
        uint2 rp; rp.x = cvtpk(win[9], win[10]); rp.y = cvtpk(win[11], 0.f);
        *(uint2*)(rmws + (size_t)s*4) = rp;
#pragma unroll
        for (int o = 0; o < 8; ++o) { acc[o] += z0[o]; acc[8+o] += z0[o]*z0[o]; }
    }
    block_reduce_atomic<16>(acc, stats);
}

// ---------------------------------------------------------------------------
// kB: load z0 -> bn0 -> z1; store z1 bf16; stats1 @ 16/24
// ---------------------------------------------------------------------------
__global__ __launch_bounds__(256)
void kB(const unsigned short* __restrict__ z0ws, const float* __restrict__ W1,
        const float* __restrict__ b1, const float* __restrict__ g0,
        const float* __restrict__ be0, float* __restrict__ stats,
        unsigned short* __restrict__ z1ws) {
    const int t = threadIdx.x;
    float acc[16];
#pragma unroll
    for (int i = 0; i < 16; ++i) acc[i] = 0.f;
#pragma unroll
    for (int i = 0; i < 4; ++i) {
        const int s = blockIdx.x*1024 + i*256 + t;
        const uint4 zz = *(const uint4*)(z0ws + (size_t)s*8);
        const unsigned short* q = (const unsigned short*)&zz;
        float z0[8];
#pragma unroll
        for (int c = 0; c < 8; ++c) z0[c] = bf2f(q[c]);
        float a0[8]; bnrelu<8>(z0, stats, g0, be0, a0);
        float z1[8]; lin<8,8>(a0, W1, b1, z1);
        uint4 zp;
        zp.x = cvtpk(z1[0], z1[1]); zp.y = cvtpk(z1[2], z1[3]);
        zp.z = cvtpk(z1[4], z1[5]); zp.w = cvtpk(z1[6], z1[7]);
        *(uint4*)(z1ws + (size_t)s*8) = zp;
#pragma unroll
        for (int o = 0; o < 8; ++o) { acc[o] += z1[o]; acc[8+o] += z1[o]*z1[o]; }
    }
    block_reduce_atomic<16>(acc, stats + 16);
}

// ---------------------------------------------------------------------------
// kC: load z1 -> bn1 -> z2 (16ch); stats2 @ 32/48 (z2 not stored)
// ---------------------------------------------------------------------------
__global__ __launch_bounds__(256)
void kC(const unsigned short* __restrict__ z1ws, const float* __restrict__ W2,
        const float* __restrict__ b2, const float* __restrict__ g1,
        const float* __restrict__ be1, float* __restrict__ stats) {
    const int t = threadIdx.x;
    float acc[32];
#pragma unroll
    for (int i = 0; i < 32; ++i) acc[i] = 0.f;
#pragma unroll
    for (int i = 0; i < 4; ++i) {
        const int s = blockIdx.x*1024 + i*256 + t;
        const uint4 zz = *(const uint4*)(z1ws + (size_t)s*8);
        const unsigned short* q = (const unsigned short*)&zz;
        float z1[8];
#pragma unroll
        for (int c = 0; c < 8; ++c) z1[c] = bf2f(q[c]);
        float a1[8];  bnrelu<8>(z1, stats + 16, g1, be1, a1);
        float z2[16]; lin<16,8>(a1, W2, b2, z2);
#pragma unroll
        for (int o = 0; o < 16; ++o) { acc[o] += z2[o]; acc[16+o] += z2[o]*z2[o]; }
    }
    block_reduce_atomic<32>(acc, stats + 32);
}

// ---------------------------------------------------------------------------
// k_fused: 16 points (256 samples) per block, 4 waves, MFMA everywhere.
// LDS: h1buf [256][40bf16] @0 (20480) -> overlaid by aggL [16][520bf16]
//      h2T [32][264bf16] @20480 (16896)
//      wBT [16p][16j][16k +pad] @37376 (8704)     total 46080 B
// ---------------------------------------------------------------------------
__global__ __launch_bounds__(256, 3)
void k_fused(const float* __restrict__ feats, const unsigned short* __restrict__ featsbf,
             const int* __restrict__ nei,
             const float* __restrict__ W2, const float* __restrict__ b2,
             const float* __restrict__ g1, const float* __restrict__ be1,
             const float* __restrict__ g2, const float* __restrict__ be2,
             const float* __restrict__ bm1, const float* __restrict__ bm2,
             const float* __restrict__ blin, const float* __restrict__ stats,
             const short* __restrict__ fWm1, const short* __restrict__ fWm2,
             const short* __restrict__ fWlin,
             const unsigned short* __restrict__ z1ws,
             const unsigned short* __restrict__ rmws,
             float* __restrict__ out) {
    __shared__ __align__(16) unsigned char smem[46080];
    const int t    = threadIdx.x;
    const int lane = t & 63;
    const int wv   = t >> 6;
    const int blk  = blockIdx.x;
    const int sbase = blk * 256;
    const int b     = (blk >= 2048) ? 1 : 0;
    const int lrow  = lane & 15;
    const int kq    = lane >> 4;

    // ---- P0: load z1 -> bn1 -> z2 -> bn2 -> w -> wBT ----
    {
        const int s = sbase + t;
        const uint4 zz = *(const uint4*)(z1ws + (size_t)s*8);
        const unsigned short* q = (const unsigned short*)&zz;
        float z1[8];
#pragma unroll
        for (int c = 0; c < 8; ++c) z1[c] = bf2f(q[c]);
        float a1[8];  bnrelu<8>(z1, stats + 16, g1, be1, a1);
        float z2[16]; lin<16,8>(a1, W2, b2, z2);
        float w[16];  bnrelu<16>(z2, stats + 32, g2, be2, w);
        const int p = t >> 4, kk = t & 15;
        unsigned short* WBT = (unsigned short*)(smem + 37376);
#pragma unroll
        for (int j = 0; j < 16; ++j)
            WBT[p*272 + j*16 + kk] = (unsigned short)f2bf(w[j]);
    }
    // no barrier: wBT consumed by the same wave (P3)

    // ---- P1: h1 = relu([gfeat,rmiu] @ Wm1^T + bm1) ----
    {
        short8 bW[3][2];
#pragma unroll
        for (int ks = 0; ks < 3; ++ks)
#pragma unroll
            for (int nt = 0; nt < 2; ++nt)
                bW[ks][nt] = *(const short8*)(fWm1 + ((ks*2 + nt)*64 + lane)*8);

        f32x4 C1[4][2];
#pragma unroll
        for (int mt = 0; mt < 4; ++mt)
#pragma unroll
            for (int nt = 0; nt < 2; ++nt)
                C1[mt][nt] = (f32x4){0.f, 0.f, 0.f, 0.f};

#pragma unroll
        for (int mt = 0; mt < 4; ++mt) {
            const int r  = wv*64 + mt*16 + lrow;
            const int sg = sbase + r;
            const int nj = nei[sg];
            const unsigned short* F = featsbf + ((size_t)(b*NN + nj)) * CC;
            const short8 a0 = *(const short8*)(F + kq*8);
            const short8 a1 = *(const short8*)(F + 32 + kq*8);
            C1[mt][0] = mfma16(a0, bW[0][0], C1[mt][0]);
            C1[mt][1] = mfma16(a0, bW[0][1], C1[mt][1]);
            C1[mt][0] = mfma16(a1, bW[1][0], C1[mt][0]);
            C1[mt][1] = mfma16(a1, bW[1][1], C1[mt][1]);
            short8 ar = (short8){0,0,0,0,0,0,0,0};
            if (kq == 0)
                *(uint2*)&ar = *(const uint2*)(rmws + (size_t)sg*4);
            C1[mt][0] = mfma16(ar, bW[2][0], C1[mt][0]);
            C1[mt][1] = mfma16(ar, bW[2][1], C1[mt][1]);
        }
        unsigned short* H1 = (unsigned short*)smem;
#pragma unroll
        for (int mt = 0; mt < 4; ++mt)
#pragma unroll
            for (int nt = 0; nt < 2; ++nt) {
                const int c = nt*16 + lrow;
                const float bias = bm1[c];
#pragma unroll
                for (int reg = 0; reg < 4; ++reg) {
                    const int s = wv*64 + mt*16 + kq*4 + reg;
                    H1[s*40 + c] = (unsigned short)f2bf(fmaxf(C1[mt][nt][reg] + bias, 0.f));
                }
            }
    }

    // ---- P2: h2 = relu(h1 @ Wm2^T + bm2) -> h2T (packed b64 stores) ----
    {
        short8 bW[2];
        bW[0] = *(const short8*)(fWm2 + (0*64 + lane)*8);
        bW[1] = *(const short8*)(fWm2 + (1*64 + lane)*8);
        const unsigned short* H1 = (const unsigned short*)smem;
        f32x4 C2[4][2];
#pragma unroll
        for (int mt = 0; mt < 4; ++mt)
#pragma unroll
            for (int nt = 0; nt < 2; ++nt)
                C2[mt][nt] = (f32x4){0.f, 0.f, 0.f, 0.f};
#pragma unroll
        for (int mt = 0; mt < 4; ++mt) {
            const int s = wv*64 + mt*16 + lrow;
            const short8 a = *(const short8*)(H1 + s*40 + kq*8);
            C2[mt][0] = mfma16(a, bW[0], C2[mt][0]);
            C2[mt][1] = mfma16(a, bW[1], C2[mt][1]);
        }
        unsigned short* H2T = (unsigned short*)(smem + 20480);
#pragma unroll
        for (int mt = 0; mt < 4; ++mt)
#pragma unroll
            for (int nt = 0; nt < 2; ++nt) {
                const int c = nt*16 + lrow;
                const float bias = bm2[c];
                const int s0 = wv*64 + mt*16 + kq*4;
                const float r0 = fmaxf(C2[mt][nt][0] + bias, 0.f);
                const float r1 = fmaxf(C2[mt][nt][1] + bias, 0.f);
                const float r2 = fmaxf(C2[mt][nt][2] + bias, 0.f);
                const float r3 = fmaxf(C2[mt][nt][3] + bias, 0.f);
                uint2 pk; pk.x = cvtpk(r0, r1); pk.y = cvtpk(r2, r3);
                *(uint2*)&H2T[c*264 + s0] = pk;
            }
    }

    __syncthreads();   // h1buf reads done before aggL overlays region 0

    // ---- P3: agg[p] = h2_p^T @ w_p -> aggL bf16 ----
    {
        const unsigned short* H2T = (const unsigned short*)(smem + 20480);
        const unsigned short* WBT = (const unsigned short*)(smem + 37376);
        unsigned short* AGG = (unsigned short*)smem;
#pragma unroll
        for (int pi = 0; pi < 4; ++pi) {
            const int p = wv*4 + pi;
            short8 bf = (short8){0,0,0,0,0,0,0,0};
            if (kq < 2)
                bf = *(const short8*)(WBT + p*272 + lrow*16 + kq*8);
#pragma unroll
            for (int ct = 0; ct < 2; ++ct) {
                short8 af = (short8){0,0,0,0,0,0,0,0};
                if (kq < 2) {
                    const int c = ct*16 + lrow;
                    af = *(const short8*)(H2T + c*264 + p*16 + kq*8);
                }
                f32x4 Cg = (f32x4){0.f, 0.f, 0.f, 0.f};
                Cg = mfma16(af, bf, Cg);
#pragma unroll
                for (int reg = 0; reg < 4; ++reg) {
                    const int c = ct*16 + kq*4 + reg;
                    AGG[p*520 + c*16 + lrow] = (unsigned short)f2bf(Cg[reg]);
                }
            }
        }
    }

    __syncthreads();   // aggL complete

    // ---- P4: out = relu(agg @ Wlin^T + blin) + feats ----
    {
        const unsigned short* AGG = (const unsigned short*)smem;
        const int nt = wv;
        f32x4 Co = (f32x4){0.f, 0.f, 0.f, 0.f};
#pragma unroll
        for (int ks = 0; ks < 16; ++ks) {
            const short8 a  = *(const short8*)(AGG + lrow*520 + ks*32 + kq*8);
            const short8 bf = *(const short8*)(fWlin + ((ks*4 + nt)*64 + lane)*8);
            Co = mfma16(a, bf, Co);
        }
        const int o = nt*16 + lrow;
        const float bias = blin[o];
#pragma unroll
        for (int reg = 0; reg < 4; ++reg) {
            const int p = kq*4 + reg;
            const size_t gp = (size_t)blk*16 + p;
            out[gp*CC + o] = fmaxf(Co[reg] + bias, 0.f) + feats[gp*CC + o];
        }
    }
}

// ---------------------------------------------------------------------------
extern "C" void kernel_launch(void* const* d_in, const int* in_sizes, int n_in,
                              void* d_out, int out_size, void* d_ws, size_t ws_size,
                              hipStream_t stream) {
    const float* xyz  = (const float*)d_in[0];
    const float* feats= (const float*)d_in[1];
    const float* xyzn = (const float*)d_in[2];
    const int*   nei  = (const int*)  d_in[3];
    const float* Wm1  = (const float*)d_in[4];
    const float* bm1  = (const float*)d_in[5];
    const float* Wm2  = (const float*)d_in[6];
    const float* bm2  = (const float*)d_in[7];
    const float* W0   = (const float*)d_in[8];
    const float* b0   = (const float*)d_in[9];
    const float* g0   = (const float*)d_in[10];
    const float* be0  = (const float*)d_in[11];
    const float* W1   = (const float*)d_in[12];
    const float* b1   = (const float*)d_in[13];
    const float* g1   = (const float*)d_in[14];
    const float* be1  = (const float*)d_in[15];
    const float* W2   = (const float*)d_in[16];
    const float* b2   = (const float*)d_in[17];
    const float* g2   = (const float*)d_in[18];
    const float* be2  = (const float*)d_in[19];
    const float* Wlin = (const float*)d_in[20];
    const float* blin = (const float*)d_in[21];

    float* out = (float*)d_out;
    char*  ws  = (char*)d_ws;

    float*          stats   = (float*)ws;                        // 256 B @ 0
    short*          fWm1    = (short*)(ws + 1024);               // 6144 B
    short*          fWm2    = (short*)(ws + 8192);               // 2048 B
    short*          fWlin   = (short*)(ws + 16384);              // 64 KB
    unsigned short* featsbf = (unsigned short*)(ws + 131072);    // 8 MB
    unsigned short* z0ws    = (unsigned short*)(ws + 8519680);   // 16 MB
    unsigned short* z1ws    = (unsigned short*)(ws + 25296896);  // 16 MB
    unsigned short* rmws    = (unsigned short*)(ws + 42074112);  // 8 MB

    hipMemsetAsync(stats, 0, 256, stream);

    k_prep<<<1024, 256, 0, stream>>>(Wm1, Wm2, Wlin, feats,
                                     fWm1, fWm2, fWlin, featsbf);
    kA<<<1024, 256, 0, stream>>>(xyz, xyzn, nei, W0, b0, z0ws, rmws, stats);
    kB<<<1024, 256, 0, stream>>>(z0ws, W1, b1, g0, be0, stats, z1ws);
    kC<<<1024, 256, 0, stream>>>(z1ws, W2, b2, g1, be1, stats);
    k_fused<<<4096, 256, 0, stream>>>(feats, featsbf, nei, W2, b2, g1, be1,
                                      g2, be2, bm1, bm2, blin, stats,
                                      fWm1, fWm2, fWlin, z1ws, rmws, out);
}

// Round 6
// 133.032 us; speedup vs baseline: 19.8081x; 1.0189x over previous
//
#include <hip/hip_runtime.h>
#include <math.h>

#define BB 2
#define NN 32768
#define KK 16
#define CC 64
#define MTOT (BB*NN*KK)   // 1048576

typedef short short8 __attribute__((ext_vector_type(8)));
typedef float f32x4 __attribute__((ext_vector_type(4)));

static_assert(MTOT == 1048576, "size");

__device__ __forceinline__ float frsq(float x) { return __builtin_amdgcn_rsqf(x); }

__device__ __forceinline__ unsigned cvtpk(float lo, float hi) {
    unsigned r;
    asm("v_cvt_pk_bf16_f32 %0, %1, %2" : "=v"(r) : "v"(lo), "v"(hi));
    return r;
}

__device__ __forceinline__ short f2bf(float f) {
    union { float f; unsigned u; } c; c.f = f;
    const unsigned r = c.u + 0x7FFFu + ((c.u >> 16) & 1u);   // RNE
    return (short)(r >> 16);
}

__device__ __forceinline__ float bf2f(unsigned short u) {
    union { unsigned u; float f; } c; c.u = ((unsigned)u) << 16; return c.f;
}

__device__ __forceinline__ f32x4 mfma16(short8 a, short8 b, f32x4 c) {
    return __builtin_amdgcn_mfma_f32_16x16x32_bf16(a, b, c, 0, 0, 0);
}

// ---------------------------------------------------------------------------
__device__ __forceinline__ void geom12(int s, const float* __restrict__ xyz,
                                       const float* __restrict__ xyzn,
                                       const int* __restrict__ nei, float* win) {
    const int pn = s >> 4;
    const int b  = pn >> 15;
    const int nj = nei[s];
    const size_t gj = (size_t)(b * NN + nj);

    const float cx = xyz[(size_t)pn*3],  cy = xyz[(size_t)pn*3+1],  cz = xyz[(size_t)pn*3+2];
    const float nmx = xyzn[(size_t)pn*3], nmy = xyzn[(size_t)pn*3+1], nmz = xyzn[(size_t)pn*3+2];
    const float gx = xyz[gj*3],  gy = xyz[gj*3+1],  gz = xyz[gj*3+2];
    const float gnx = xyzn[gj*3], gny = xyzn[gj*3+1], gnz = xyzn[gj*3+2];

    const float rx = gx - cx, ry = gy - cy, rz = gz - cz;
    const float ss = rx*rx + ry*ry + rz*rz;
    const float rinv = frsq(fmaxf(ss, 1e-24f));
    const float rlen = ss * rinv;
    const float rhx = rx*rinv, rhy = ry*rinv, rhz = rz*rinv;

    const float d_nr = nmx*rhx + nmy*rhy + nmz*rhz;
    float vx = nmx - d_nr*rhx, vy = nmy - d_nr*rhy, vz = nmz - d_nr*rhz;
    const float vinv = frsq(fmaxf(vx*vx + vy*vy + vz*vz, 1e-24f));
    vx *= vinv; vy *= vinv; vz *= vinv;

    float wx = rhy*vz - rhz*vy;
    float wy = rhz*vx - rhx*vz;
    float wz = rhx*vy - rhy*vx;
    const float winv = frsq(fmaxf(wx*wx + wy*wy + wz*wz, 1e-24f));
    wx *= winv; wy *= winv; wz *= winv;

    const float th1 = gnx*nmx + gny*nmy + gnz*nmz;
    const float th3 = rhx*gnx + rhy*gny + rhz*gnz;
    const float th4 = rx*nmx + ry*nmy + rz*nmz;
    const float th6 = gnx*vx + gny*vy + gnz*vz;
    const float th7 = gnx*wx + gny*wy + gnz*wz;
    const float ccx = gny*nmz - gnz*nmy;
    const float ccy = gnz*nmx - gnx*nmz;
    const float ccz = gnx*nmy - gny*nmx;
    const float th8 = rx*ccx + ry*ccy + rz*ccz;

    win[0]=th1; win[1]=d_nr; win[2]=th3; win[3]=th4; win[4]=th3; win[5]=th6;
    win[6]=th7; win[7]=th8; win[8]=rlen; win[9]=rx; win[10]=ry; win[11]=rz;
}

template<int ON, int IN>
__device__ __forceinline__ void lin(const float* a, const float* __restrict__ W,
                                    const float* __restrict__ bias, float* z) {
#pragma unroll
    for (int o = 0; o < ON; ++o) {
        float acc = bias[o];
#pragma unroll
        for (int c = 0; c < IN; ++c) acc += a[c] * W[o*IN + c];
        z[o] = acc;
    }
}

template<int NV>
__device__ __forceinline__ void block_reduce_atomic(const float* v, float* gdst) {
    __shared__ float red[NV * 4];
    const int lane = threadIdx.x & 63;
    const int wv   = threadIdx.x >> 6;
    float tmp[NV];
#pragma unroll
    for (int i = 0; i < NV; ++i) {
        float x = v[i];
#pragma unroll
        for (int off = 32; off > 0; off >>= 1) x += __shfl_down(x, off, 64);
        tmp[i] = x;
    }
    if (lane == 0) {
#pragma unroll
        for (int i = 0; i < NV; ++i) red[wv * NV + i] = tmp[i];
    }
    __syncthreads();
    if (threadIdx.x < NV) {
        float s = red[threadIdx.x] + red[NV + threadIdx.x] +
                  red[2*NV + threadIdx.x] + red[3*NV + threadIdx.x];
        atomicAdd(gdst + threadIdx.x, s);
    }
}

// ---------------------------------------------------------------------------
// kA: prep (R4-style weight frags + featsbf) + geometry -> z0 bf16 + rm4 + stats0
// ---------------------------------------------------------------------------
__global__ __launch_bounds__(256)
void kA(const float* __restrict__ xyz, const float* __restrict__ xyzn,
        const int* __restrict__ nei, const float* __restrict__ W0,
        const float* __restrict__ b0,
        const float* __restrict__ Wm1, const float* __restrict__ Wm2,
        const float* __restrict__ Wlin, const float* __restrict__ feats,
        unsigned short* __restrict__ z0ws, unsigned short* __restrict__ rmws,
        short* __restrict__ fWm1, short* __restrict__ fWm2,
        short* __restrict__ fWlin, unsigned short* __restrict__ featsbf,
        float* __restrict__ stats) {
    const int t = threadIdx.x;
    const int gid  = blockIdx.x * 256 + t;
    const int gstr = gridDim.x * 256;

    for (int i = gid; i < 3072; i += gstr) {          // Wm1^T [96pad x 32]
        const int j = i & 7, l = (i >> 3) & 63, fn = i >> 9;
        const int ks = fn >> 1, nt = fn & 1;
        const int k = ks*32 + ((l >> 4) * 8) + j, n = nt*16 + (l & 15);
        fWm1[i] = (k < 67) ? f2bf(Wm1[n*67 + k]) : (short)0;
    }
    for (int i = gid; i < 1024; i += gstr) {          // Wm2^T [32 x 32]
        const int j = i & 7, l = (i >> 3) & 63, nt = i >> 9;
        const int k = ((l >> 4) * 8) + j, n = nt*16 + (l & 15);
        fWm2[i] = f2bf(Wm2[n*32 + k]);
    }
    for (int i = gid; i < 32768; i += gstr) {         // Wlin^T [512 x 64] (R4: no permute)
        const int j = i & 7, l = (i >> 3) & 63, fn = i >> 9;
        const int ks = fn >> 2, nt = fn & 3;
        const int k = ks*32 + ((l >> 4) * 8) + j, n = nt*16 + (l & 15);
        fWlin[i] = f2bf(Wlin[n*512 + k]);
    }
    for (int i = gid; i < (BB*NN*CC)/4; i += gstr) {  // feats -> bf16
        const float4 f = *(const float4*)(feats + (size_t)i*4);
        uint2 p; p.x = cvtpk(f.x, f.y); p.y = cvtpk(f.z, f.w);
        *(uint2*)(featsbf + (size_t)i*4) = p;
    }

    float acc[16];
#pragma unroll
    for (int i = 0; i < 16; ++i) acc[i] = 0.f;
#pragma unroll
    for (int i = 0; i < 4; ++i) {
        const int s = blockIdx.x*1024 + i*256 + t;
        float win[12]; geom12(s, xyz, xyzn, nei, win);
        float z0[8];  lin<8,12>(win, W0, b0, z0);
        uint4 zp;
        zp.x = cvtpk(z0[0], z0[1]); zp.y = cvtpk(z0[2], z0[3]);
        zp.z = cvtpk(z0[4], z0[5]); zp.w = cvtpk(z0[6], z0[7]);
        *(uint4*)(z0ws + (size_t)s*8) = zp;
        uint2 rp; rp.x = cvtpk(win[9], win[10]); rp.y = cvtpk(win[11], 0.0f);
        *(uint2*)(rmws + (size_t)s*4) = rp;
#pragma unroll
        for (int o = 0; o < 8; ++o) { acc[o] += z0[o]; acc[8+o] += z0[o]*z0[o]; }
    }
    block_reduce_atomic<16>(acc, stats);
}

// ---------------------------------------------------------------------------
// kB: z0 -> a0 (hoisted BN coefs) -> z1; stats1 only (no z1 store)
// ---------------------------------------------------------------------------
__global__ __launch_bounds__(256)
void kB(const unsigned short* __restrict__ z0ws, const float* __restrict__ W1,
        const float* __restrict__ b1, const float* __restrict__ g0,
        const float* __restrict__ be0, const float* __restrict__ stats0,
        float* __restrict__ statsOut) {
    const int t = threadIdx.x;
    const float invM = 1.0f / (float)MTOT;
    float sc0[8], sh0[8];
#pragma unroll
    for (int c = 0; c < 8; ++c) {
        const float m = stats0[c] * invM;
        const float v = stats0[8 + c] * invM - m*m;
        const float s = frsq(v + 1e-5f) * g0[c];
        sc0[c] = s; sh0[c] = be0[c] - m*s;
    }
    float acc[16];
#pragma unroll
    for (int i = 0; i < 16; ++i) acc[i] = 0.f;
#pragma unroll
    for (int i = 0; i < 4; ++i) {
        const int s = blockIdx.x*1024 + i*256 + t;
        const uint4 zz = *(const uint4*)(z0ws + (size_t)s*8);
        const unsigned short* q = (const unsigned short*)&zz;
        float a0[8];
#pragma unroll
        for (int c = 0; c < 8; ++c) a0[c] = fmaxf(bf2f(q[c])*sc0[c] + sh0[c], 0.f);
        float z1[8]; lin<8,8>(a0, W1, b1, z1);
#pragma unroll
        for (int o = 0; o < 8; ++o) { acc[o] += z1[o]; acc[8+o] += z1[o]*z1[o]; }
    }
    block_reduce_atomic<16>(acc, statsOut);
}

// ---------------------------------------------------------------------------
// kC: z0 -> a0 -> z1 -> a1 -> z2; stats2 (hoisted coefs for bn0, bn1)
// ---------------------------------------------------------------------------
__global__ __launch_bounds__(256)
void kC(const unsigned short* __restrict__ z0ws, const float* __restrict__ W1,
        const float* __restrict__ b1, const float* __restrict__ W2,
        const float* __restrict__ b2, const float* __restrict__ g0,
        const float* __restrict__ be0, const float* __restrict__ g1,
        const float* __restrict__ be1, const float* __restrict__ stats0,
        float* __restrict__ statsOut) {
    const int t = threadIdx.x;
    const float invM = 1.0f / (float)MTOT;
    float sc0[8], sh0[8], sc1[8], sh1[8];
#pragma unroll
    for (int c = 0; c < 8; ++c) {
        float m = stats0[c] * invM;
        float v = stats0[8 + c] * invM - m*m;
        float s = frsq(v + 1e-5f) * g0[c];
        sc0[c] = s; sh0[c] = be0[c] - m*s;
        m = stats0[16 + c] * invM;
        v = stats0[24 + c] * invM - m*m;
        s = frsq(v + 1e-5f) * g1[c];
        sc1[c] = s; sh1[c] = be1[c] - m*s;
    }
    float acc[32];
#pragma unroll
    for (int i = 0; i < 32; ++i) acc[i] = 0.f;
#pragma unroll
    for (int i = 0; i < 4; ++i) {
        const int s = blockIdx.x*1024 + i*256 + t;
        const uint4 zz = *(const uint4*)(z0ws + (size_t)s*8);
        const unsigned short* q = (const unsigned short*)&zz;
        float a0[8];
#pragma unroll
        for (int c = 0; c < 8; ++c) a0[c] = fmaxf(bf2f(q[c])*sc0[c] + sh0[c], 0.f);
        float z1[8]; lin<8,8>(a0, W1, b1, z1);
        float a1[8];
#pragma unroll
        for (int c = 0; c < 8; ++c) a1[c] = fmaxf(z1[c]*sc1[c] + sh1[c], 0.f);
        float z2[16]; lin<16,8>(a1, W2, b2, z2);
#pragma unroll
        for (int o = 0; o < 16; ++o) { acc[o] += z2[o]; acc[16+o] += z2[o]*z2[o]; }
    }
    block_reduce_atomic<32>(acc, statsOut);
}

// ---------------------------------------------------------------------------
// k_fin: fold BN coefficients into linear weights (1 block)
// fold: [0..7]=sc0 [8..15]=sh0 [16..79]=W1f [80..87]=b1f [88..215]=W2f [216..231]=b2f
// ---------------------------------------------------------------------------
__global__ void k_fin(const float* __restrict__ stats,
                      const float* __restrict__ g0, const float* __restrict__ be0,
                      const float* __restrict__ W1, const float* __restrict__ b1,
                      const float* __restrict__ g1, const float* __restrict__ be1,
                      const float* __restrict__ W2, const float* __restrict__ b2,
                      const float* __restrict__ g2, const float* __restrict__ be2,
                      float* __restrict__ fold) {
    __shared__ float sc[32], sh[32];
    const int t = threadIdx.x;
    const float invM = 1.0f / (float)MTOT;
    if (t < 8) {
        const float m = stats[t]*invM, v = stats[8+t]*invM - m*m;
        const float s = frsq(v + 1e-5f) * g0[t];
        sc[t] = s; sh[t] = be0[t] - m*s;
    } else if (t < 16) {
        const int c = t - 8;
        const float m = stats[16+c]*invM, v = stats[24+c]*invM - m*m;
        const float s = frsq(v + 1e-5f) * g1[c];
        sc[t] = s; sh[t] = be1[c] - m*s;
    } else if (t < 32) {
        const int c = t - 16;
        const float m = stats[32+c]*invM, v = stats[48+c]*invM - m*m;
        const float s = frsq(v + 1e-5f) * g2[c];
        sc[t] = s; sh[t] = be2[c] - m*s;
    }
    __syncthreads();
    if (t < 8)   { fold[t] = sc[t]; fold[8+t] = sh[t]; }
    if (t < 64)  fold[16 + t] = sc[8 + (t >> 3)] * W1[t];
    if (t < 8)   fold[80 + t] = sc[8 + t]*b1[t] + sh[8 + t];
    if (t < 128) fold[88 + t] = sc[16 + (t >> 3)] * W2[t];
    if (t < 16)  fold[216 + t] = sc[16 + t]*b2[t] + sh[16 + t];
}

// ---------------------------------------------------------------------------
// k_fused: R4 structure (both barriers, R4 P1/P2/P3/P4) + fold-based P0.
// LDS: h1buf [256][40bf16] @0 (20480) -> overlaid by aggL [16][520bf16]
//      h2T [32][264bf16] @20480 (16896);  wBT [16p][272bf16] @37376 (8704)
// ---------------------------------------------------------------------------
__global__ __launch_bounds__(256, 3)
void k_fused(const float* __restrict__ feats,
             const unsigned short* __restrict__ featsbf,
             const int* __restrict__ nei,
             const float* __restrict__ bm1, const float* __restrict__ bm2,
             const float* __restrict__ blin, const float* __restrict__ fold,
             const short* __restrict__ fWm1, const short* __restrict__ fWm2,
             const short* __restrict__ fWlin,
             const unsigned short* __restrict__ z0ws,
             const unsigned short* __restrict__ rmws,
             float* __restrict__ out) {
    __shared__ __align__(16) unsigned char smem[46080];
    const int t    = threadIdx.x;
    const int lane = t & 63;
    const int wv   = t >> 6;
    const int blk  = blockIdx.x;
    const int sbase = blk * 256;
    const int b     = (blk >= 2048) ? 1 : 0;
    const int lrow  = lane & 15;
    const int kq    = lane >> 4;

    // ---- P0: z0 -> folded wn chain -> w -> wBT ----
    {
        const int s = sbase + t;
        const uint4 zz = *(const uint4*)(z0ws + (size_t)s*8);
        const unsigned short* q = (const unsigned short*)&zz;
        float a0[8];
#pragma unroll
        for (int c = 0; c < 8; ++c) a0[c] = fmaxf(bf2f(q[c])*fold[c] + fold[8+c], 0.f);
        float a1[8];
#pragma unroll
        for (int o = 0; o < 8; ++o) {
            float acc = fold[80 + o];
#pragma unroll
            for (int c = 0; c < 8; ++c) acc += a0[c] * fold[16 + o*8 + c];
            a1[o] = fmaxf(acc, 0.f);
        }
        const int p = t >> 4, kk = t & 15;
        unsigned short* WBT = (unsigned short*)(smem + 37376);
#pragma unroll
        for (int o = 0; o < 16; ++o) {
            float acc = fold[216 + o];
#pragma unroll
            for (int c = 0; c < 8; ++c) acc += a1[c] * fold[88 + o*8 + c];
            WBT[p*272 + o*16 + kk] = (unsigned short)f2bf(fmaxf(acc, 0.f));
        }
    }

    // ---- P1: h1 = relu([gfeat,rmiu] @ Wm1^T + bm1)  (R4 verbatim) ----
    {
        short8 bW[3][2];
#pragma unroll
        for (int ks = 0; ks < 3; ++ks)
#pragma unroll
            for (int nt = 0; nt < 2; ++nt)
                bW[ks][nt] = *(const short8*)(fWm1 + ((ks*2 + nt)*64 + lane)*8);

        f32x4 C1[4][2];
#pragma unroll
        for (int mt = 0; mt < 4; ++mt)
#pragma unroll
            for (int nt = 0; nt < 2; ++nt)
                C1[mt][nt] = (f32x4){0.f, 0.f, 0.f, 0.f};

#pragma unroll
        for (int mt = 0; mt < 4; ++mt) {
            const int r  = wv*64 + mt*16 + lrow;
            const int sg = sbase + r;
            const int nj = nei[sg];
            const unsigned short* F = featsbf + ((size_t)(b*NN + nj)) * CC;
            const short8 a0 = *(const short8*)(F + kq*8);
            const short8 a1 = *(const short8*)(F + 32 + kq*8);
            C1[mt][0] = mfma16(a0, bW[0][0], C1[mt][0]);
            C1[mt][1] = mfma16(a0, bW[0][1], C1[mt][1]);
            C1[mt][0] = mfma16(a1, bW[1][0], C1[mt][0]);
            C1[mt][1] = mfma16(a1, bW[1][1], C1[mt][1]);
            short8 ar = (short8){0,0,0,0,0,0,0,0};
            if (kq == 0)
                *(uint2*)&ar = *(const uint2*)(rmws + (size_t)sg*4);
            C1[mt][0] = mfma16(ar, bW[2][0], C1[mt][0]);
            C1[mt][1] = mfma16(ar, bW[2][1], C1[mt][1]);
        }
        unsigned short* H1 = (unsigned short*)smem;
#pragma unroll
        for (int mt = 0; mt < 4; ++mt)
#pragma unroll
            for (int nt = 0; nt < 2; ++nt) {
                const int c = nt*16 + lrow;
                const float bias = bm1[c];
#pragma unroll
                for (int reg = 0; reg < 4; ++reg) {
                    const int s = wv*64 + mt*16 + kq*4 + reg;
                    H1[s*40 + c] = (unsigned short)f2bf(fmaxf(C1[mt][nt][reg] + bias, 0.f));
                }
            }
    }

    // ---- P2: h2 = relu(h1 @ fWm2 + bm2) -> h2T (R4 verbatim) ----
    {
        short8 bW[2];
        bW[0] = *(const short8*)(fWm2 + (0*64 + lane)*8);
        bW[1] = *(const short8*)(fWm2 + (1*64 + lane)*8);
        const unsigned short* H1 = (const unsigned short*)smem;
        f32x4 C2[4][2];
#pragma unroll
        for (int mt = 0; mt < 4; ++mt)
#pragma unroll
            for (int nt = 0; nt < 2; ++nt)
                C2[mt][nt] = (f32x4){0.f, 0.f, 0.f, 0.f};
#pragma unroll
        for (int mt = 0; mt < 4; ++mt) {
            const int s = wv*64 + mt*16 + lrow;
            const short8 a = *(const short8*)(H1 + s*40 + kq*8);
            C2[mt][0] = mfma16(a, bW[0], C2[mt][0]);
            C2[mt][1] = mfma16(a, bW[1], C2[mt][1]);
        }
        unsigned short* H2T = (unsigned short*)(smem + 20480);
#pragma unroll
        for (int mt = 0; mt < 4; ++mt)
#pragma unroll
            for (int nt = 0; nt < 2; ++nt) {
                const int c = nt*16 + lrow;
                const float bias = bm2[c];
                const int s0 = wv*64 + mt*16 + kq*4;
                const float r0 = fmaxf(C2[mt][nt][0] + bias, 0.f);
                const float r1 = fmaxf(C2[mt][nt][1] + bias, 0.f);
                const float r2 = fmaxf(C2[mt][nt][2] + bias, 0.f);
                const float r3 = fmaxf(C2[mt][nt][3] + bias, 0.f);
                uint2 pk; pk.x = cvtpk(r0, r1); pk.y = cvtpk(r2, r3);
                *(uint2*)&H2T[c*264 + s0] = pk;
            }
    }

    __syncthreads();   // h1buf reads done before aggL overlays region 0

    // ---- P3: agg[p] = h2_p^T @ w_p -> aggL [p][c*16+j] bf16 (R4 verbatim) ----
    {
        const unsigned short* H2T = (const unsigned short*)(smem + 20480);
        const unsigned short* WBT = (const unsigned short*)(smem + 37376);
        unsigned short* AGG = (unsigned short*)smem;
#pragma unroll
        for (int pi = 0; pi < 4; ++pi) {
            const int p = wv*4 + pi;
            short8 bf = (short8){0,0,0,0,0,0,0,0};
            if (kq < 2)
                bf = *(const short8*)(WBT + p*272 + lrow*16 + kq*8);
#pragma unroll
            for (int ct = 0; ct < 2; ++ct) {
                short8 af = (short8){0,0,0,0,0,0,0,0};
                if (kq < 2) {
                    const int c = ct*16 + lrow;
                    af = *(const short8*)(H2T + c*264 + p*16 + kq*8);
                }
                f32x4 Cg = (f32x4){0.f, 0.f, 0.f, 0.f};
                Cg = mfma16(af, bf, Cg);
#pragma unroll
                for (int reg = 0; reg < 4; ++reg) {
                    const int c = ct*16 + kq*4 + reg;
                    AGG[p*520 + c*16 + lrow] = (unsigned short)f2bf(Cg[reg]);
                }
            }
        }
    }

    __syncthreads();   // aggL complete

    // ---- P4: out = relu(agg @ Wlin^T + blin) + feats (R4 verbatim) ----
    {
        const unsigned short* AGG = (const unsigned short*)smem;
        const int nt = wv;
        f32x4 Co = (f32x4){0.f, 0.f, 0.f, 0.f};
#pragma unroll
        for (int ks = 0; ks < 16; ++ks) {
            const short8 a  = *(const short8*)(AGG + lrow*520 + ks*32 + kq*8);
            const short8 bf = *(const short8*)(fWlin + ((ks*4 + nt)*64 + lane)*8);
            Co = mfma16(a, bf, Co);
        }
        const int o = nt*16 + lrow;
        const float bias = blin[o];
#pragma unroll
        for (int reg = 0; reg < 4; ++reg) {
            const int p = kq*4 + reg;
            const size_t gp = (size_t)blk*16 + p;
            out[gp*CC + o] = fmaxf(Co[reg] + bias, 0.f) + feats[gp*CC + o];
        }
    }
}

// ---------------------------------------------------------------------------
extern "C" void kernel_launch(void* const* d_in, const int* in_sizes, int n_in,
                              void* d_out, int out_size, void* d_ws, size_t ws_size,
                              hipStream_t stream) {
    const float* xyz  = (const float*)d_in[0];
    const float* feats= (const float*)d_in[1];
    const float* xyzn = (const float*)d_in[2];
    const int*   nei  = (const int*)  d_in[3];
    const float* Wm1  = (const float*)d_in[4];
    const float* bm1  = (const float*)d_in[5];
    const float* Wm2  = (const float*)d_in[6];
    const float* bm2  = (const float*)d_in[7];
    const float* W0   = (const float*)d_in[8];
    const float* b0   = (const float*)d_in[9];
    const float* g0   = (const float*)d_in[10];
    const float* be0  = (const float*)d_in[11];
    const float* W1   = (const float*)d_in[12];
    const float* b1   = (const float*)d_in[13];
    const float* g1   = (const float*)d_in[14];
    const float* be1  = (const float*)d_in[15];
    const float* W2   = (const float*)d_in[16];
    const float* b2   = (const float*)d_in[17];
    const float* g2   = (const float*)d_in[18];
    const float* be2  = (const float*)d_in[19];
    const float* Wlin = (const float*)d_in[20];
    const float* blin = (const float*)d_in[21];

    float* out = (float*)d_out;
    char*  ws  = (char*)d_ws;

    float*          stats   = (float*)ws;                        // 256 B @ 0
    float*          fold    = (float*)(ws + 256);                // 232 f
    short*          fWm1    = (short*)(ws + 2048);               // 6144 B
    short*          fWm2    = (short*)(ws + 8192);               // 2048 B
    short*          fWlin   = (short*)(ws + 16384);              // 64 KB
    unsigned short* featsbf = (unsigned short*)(ws + 131072);    // 8 MB
    unsigned short* z0ws    = (unsigned short*)(ws + 8519680);   // 16 MB
    unsigned short* rmws    = (unsigned short*)(ws + 25296896);  // 8 MB

    hipMemsetAsync(stats, 0, 256, stream);

    kA<<<1024, 256, 0, stream>>>(xyz, xyzn, nei, W0, b0, Wm1, Wm2, Wlin,
                                 feats, z0ws, rmws, fWm1, fWm2, fWlin,
                                 featsbf, stats);
    kB<<<1024, 256, 0, stream>>>(z0ws, W1, b1, g0, be0, stats, stats + 16);
    kC<<<1024, 256, 0, stream>>>(z0ws, W1, b1, W2, b2, g0, be0, g1, be1,
                                 stats, stats + 32);
    k_fin<<<1, 256, 0, stream>>>(stats, g0, be0, W1, b1, g1, be1,
                                 W2, b2, g2, be2, fold);
    k_fused<<<4096, 256, 0, stream>>>(feats, featsbf, nei, bm1, bm2, blin,
                                      fold, fWm1, fWm2, fWlin, z0ws, rmws, out);
}

// Round 8
// 124.075 us; speedup vs baseline: 21.2380x; 1.0722x over previous
//
#include <hip/hip_runtime.h>
#include <math.h>

#define BB 2
#define NN 32768
#define KK 16
#define CC 64
#define MTOT (BB*NN*KK)   // 1048576

typedef short short8 __attribute__((ext_vector_type(8)));
typedef float f32x4 __attribute__((ext_vector_type(4)));

static_assert(MTOT == 1048576, "size");

__device__ __forceinline__ float frsq(float x) { return __builtin_amdgcn_rsqf(x); }

__device__ __forceinline__ unsigned cvtpk(float lo, float hi) {
    unsigned r;
    asm("v_cvt_pk_bf16_f32 %0, %1, %2" : "=v"(r) : "v"(lo), "v"(hi));
    return r;
}

__device__ __forceinline__ short f2bf(float f) {
    union { float f; unsigned u; } c; c.f = f;
    const unsigned r = c.u + 0x7FFFu + ((c.u >> 16) & 1u);   // RNE
    return (short)(r >> 16);
}

__device__ __forceinline__ float bf2f(unsigned short u) {
    union { unsigned u; float f; } c; c.u = ((unsigned)u) << 16; return c.f;
}

__device__ __forceinline__ f32x4 mfma16(short8 a, short8 b, f32x4 c) {
    return __builtin_amdgcn_mfma_f32_16x16x32_bf16(a, b, c, 0, 0, 0);
}

// ---------------------------------------------------------------------------
__device__ __forceinline__ void geom12(int s, const float* __restrict__ xyz,
                                       const float* __restrict__ xyzn,
                                       const int* __restrict__ nei, float* win) {
    const int pn = s >> 4;
    const int b  = pn >> 15;
    const int nj = nei[s];
    const size_t gj = (size_t)(b * NN + nj);

    const float cx = xyz[(size_t)pn*3],  cy = xyz[(size_t)pn*3+1],  cz = xyz[(size_t)pn*3+2];
    const float nmx = xyzn[(size_t)pn*3], nmy = xyzn[(size_t)pn*3+1], nmz = xyzn[(size_t)pn*3+2];
    const float gx = xyz[gj*3],  gy = xyz[gj*3+1],  gz = xyz[gj*3+2];
    const float gnx = xyzn[gj*3], gny = xyzn[gj*3+1], gnz = xyzn[gj*3+2];

    const float rx = gx - cx, ry = gy - cy, rz = gz - cz;
    const float ss = rx*rx + ry*ry + rz*rz;
    const float rinv = frsq(fmaxf(ss, 1e-24f));
    const float rlen = ss * rinv;
    const float rhx = rx*rinv, rhy = ry*rinv, rhz = rz*rinv;

    const float d_nr = nmx*rhx + nmy*rhy + nmz*rhz;
    float vx = nmx - d_nr*rhx, vy = nmy - d_nr*rhy, vz = nmz - d_nr*rhz;
    const float vinv = frsq(fmaxf(vx*vx + vy*vy + vz*vz, 1e-24f));
    vx *= vinv; vy *= vinv; vz *= vinv;

    float wx = rhy*vz - rhz*vy;
    float wy = rhz*vx - rhx*vz;
    float wz = rhx*vy - rhy*vx;
    const float winv = frsq(fmaxf(wx*wx + wy*wy + wz*wz, 1e-24f));
    wx *= winv; wy *= winv; wz *= winv;

    const float th1 = gnx*nmx + gny*nmy + gnz*nmz;
    const float th3 = rhx*gnx + rhy*gny + rhz*gnz;
    const float th4 = rx*nmx + ry*nmy + rz*nmz;
    const float th6 = gnx*vx + gny*vy + gnz*vz;
    const float th7 = gnx*wx + gny*wy + gnz*wz;
    const float ccx = gny*nmz - gnz*nmy;
    const float ccy = gnz*nmx - gnx*nmz;
    const float ccz = gnx*nmy - gny*nmx;
    const float th8 = rx*ccx + ry*ccy + rz*ccz;

    win[0]=th1; win[1]=d_nr; win[2]=th3; win[3]=th4; win[4]=th3; win[5]=th6;
    win[6]=th7; win[7]=th8; win[8]=rlen; win[9]=rx; win[10]=ry; win[11]=rz;
}

template<int ON, int IN>
__device__ __forceinline__ void lin(const float* a, const float* __restrict__ W,
                                    const float* __restrict__ bias, float* z) {
#pragma unroll
    for (int o = 0; o < ON; ++o) {
        float acc = bias[o];
#pragma unroll
        for (int c = 0; c < IN; ++c) acc += a[c] * W[o*IN + c];
        z[o] = acc;
    }
}

template<int NV>
__device__ __forceinline__ void block_reduce_atomic(const float* v, float* gdst) {
    __shared__ float red[NV * 4];
    const int lane = threadIdx.x & 63;
    const int wv   = threadIdx.x >> 6;
    float tmp[NV];
#pragma unroll
    for (int i = 0; i < NV; ++i) {
        float x = v[i];
#pragma unroll
        for (int off = 32; off > 0; off >>= 1) x += __shfl_down(x, off, 64);
        tmp[i] = x;
    }
    if (lane == 0) {
#pragma unroll
        for (int i = 0; i < NV; ++i) red[wv * NV + i] = tmp[i];
    }
    __syncthreads();
    if (threadIdx.x < NV) {
        float s = red[threadIdx.x] + red[NV + threadIdx.x] +
                  red[2*NV + threadIdx.x] + red[3*NV + threadIdx.x];
        atomicAdd(gdst + threadIdx.x, s);
    }
}

// ---------------------------------------------------------------------------
// kA: prep (weight frags + featsbf) + geometry -> z0 bf16 + rm4 + stats0
// ---------------------------------------------------------------------------
__global__ __launch_bounds__(256)
void kA(const float* __restrict__ xyz, const float* __restrict__ xyzn,
        const int* __restrict__ nei, const float* __restrict__ W0,
        const float* __restrict__ b0,
        const float* __restrict__ Wm1, const float* __restrict__ Wm2,
        const float* __restrict__ Wlin, const float* __restrict__ feats,
        unsigned short* __restrict__ z0ws, unsigned short* __restrict__ rmws,
        short* __restrict__ fWm1, short* __restrict__ fWm2,
        short* __restrict__ fWlin, unsigned short* __restrict__ featsbf,
        float* __restrict__ stats) {
    const int t = threadIdx.x;
    const int gid  = blockIdx.x * 256 + t;
    const int gstr = gridDim.x * 256;

    for (int i = gid; i < 3072; i += gstr) {          // Wm1^T [96pad x 32]
        const int j = i & 7, l = (i >> 3) & 63, fn = i >> 9;
        const int ks = fn >> 1, nt = fn & 1;
        const int k = ks*32 + ((l >> 4) * 8) + j, n = nt*16 + (l & 15);
        fWm1[i] = (k < 67) ? f2bf(Wm1[n*67 + k]) : (short)0;
    }
    for (int i = gid; i < 1024; i += gstr) {          // Wm2^T [32 x 32]
        const int j = i & 7, l = (i >> 3) & 63, nt = i >> 9;
        const int k = ((l >> 4) * 8) + j, n = nt*16 + (l & 15);
        fWm2[i] = f2bf(Wm2[n*32 + k]);
    }
    for (int i = gid; i < 32768; i += gstr) {         // Wlin^T [512 x 64]
        const int j = i & 7, l = (i >> 3) & 63, fn = i >> 9;
        const int ks = fn >> 2, nt = fn & 3;
        const int k = ks*32 + ((l >> 4) * 8) + j, n = nt*16 + (l & 15);
        fWlin[i] = f2bf(Wlin[n*512 + k]);
    }
    for (int i = gid; i < (BB*NN*CC)/4; i += gstr) {  // feats -> bf16
        const float4 f = *(const float4*)(feats + (size_t)i*4);
        uint2 p; p.x = cvtpk(f.x, f.y); p.y = cvtpk(f.z, f.w);
        *(uint2*)(featsbf + (size_t)i*4) = p;
    }

    float acc[16];
#pragma unroll
    for (int i = 0; i < 16; ++i) acc[i] = 0.f;
#pragma unroll
    for (int i = 0; i < 4; ++i) {
        const int s = blockIdx.x*1024 + i*256 + t;
        float win[12]; geom12(s, xyz, xyzn, nei, win);
        float z0[8];  lin<8,12>(win, W0, b0, z0);
        uint4 zp;
        zp.x = cvtpk(z0[0], z0[1]); zp.y = cvtpk(z0[2], z0[3]);
        zp.z = cvtpk(z0[4], z0[5]); zp.w = cvtpk(z0[6], z0[7]);
        *(uint4*)(z0ws + (size_t)s*8) = zp;
        uint2 rp; rp.x = cvtpk(win[9], win[10]); rp.y = cvtpk(win[11], 0.0f);
        *(uint2*)(rmws + (size_t)s*4) = rp;
#pragma unroll
        for (int o = 0; o < 8; ++o) { acc[o] += z0[o]; acc[8+o] += z0[o]*z0[o]; }
    }
    block_reduce_atomic<16>(acc, stats);
}

// ---------------------------------------------------------------------------
// kB: z0 -> a0 (hoisted BN coefs) -> z1; stats1 only
// ---------------------------------------------------------------------------
__global__ __launch_bounds__(256)
void kB(const unsigned short* __restrict__ z0ws, const float* __restrict__ W1,
        const float* __restrict__ b1, const float* __restrict__ g0,
        const float* __restrict__ be0, const float* __restrict__ stats0,
        float* __restrict__ statsOut) {
    const int t = threadIdx.x;
    const float invM = 1.0f / (float)MTOT;
    float sc0[8], sh0[8];
#pragma unroll
    for (int c = 0; c < 8; ++c) {
        const float m = stats0[c] * invM;
        const float v = stats0[8 + c] * invM - m*m;
        const float s = frsq(v + 1e-5f) * g0[c];
        sc0[c] = s; sh0[c] = be0[c] - m*s;
    }
    float acc[16];
#pragma unroll
    for (int i = 0; i < 16; ++i) acc[i] = 0.f;
#pragma unroll
    for (int i = 0; i < 4; ++i) {
        const int s = blockIdx.x*1024 + i*256 + t;
        const uint4 zz = *(const uint4*)(z0ws + (size_t)s*8);
        const unsigned short* q = (const unsigned short*)&zz;
        float a0[8];
#pragma unroll
        for (int c = 0; c < 8; ++c) a0[c] = fmaxf(bf2f(q[c])*sc0[c] + sh0[c], 0.f);
        float z1[8]; lin<8,8>(a0, W1, b1, z1);
#pragma unroll
        for (int o = 0; o < 8; ++o) { acc[o] += z1[o]; acc[8+o] += z1[o]*z1[o]; }
    }
    block_reduce_atomic<16>(acc, statsOut);
}

// ---------------------------------------------------------------------------
// kC: z0 -> a0 -> z1 -> a1 -> z2; stats2
// ---------------------------------------------------------------------------
__global__ __launch_bounds__(256)
void kC(const unsigned short* __restrict__ z0ws, const float* __restrict__ W1,
        const float* __restrict__ b1, const float* __restrict__ W2,
        const float* __restrict__ b2, const float* __restrict__ g0,
        const float* __restrict__ be0, const float* __restrict__ g1,
        const float* __restrict__ be1, const float* __restrict__ stats0,
        float* __restrict__ statsOut) {
    const int t = threadIdx.x;
    const float invM = 1.0f / (float)MTOT;
    float sc0[8], sh0[8], sc1[8], sh1[8];
#pragma unroll
    for (int c = 0; c < 8; ++c) {
        float m = stats0[c] * invM;
        float v = stats0[8 + c] * invM - m*m;
        float s = frsq(v + 1e-5f) * g0[c];
        sc0[c] = s; sh0[c] = be0[c] - m*s;
        m = stats0[16 + c] * invM;
        v = stats0[24 + c] * invM - m*m;
        s = frsq(v + 1e-5f) * g1[c];
        sc1[c] = s; sh1[c] = be1[c] - m*s;
    }
    float acc[32];
#pragma unroll
    for (int i = 0; i < 32; ++i) acc[i] = 0.f;
#pragma unroll
    for (int i = 0; i < 4; ++i) {
        const int s = blockIdx.x*1024 + i*256 + t;
        const uint4 zz = *(const uint4*)(z0ws + (size_t)s*8);
        const unsigned short* q = (const unsigned short*)&zz;
        float a0[8];
#pragma unroll
        for (int c = 0; c < 8; ++c) a0[c] = fmaxf(bf2f(q[c])*sc0[c] + sh0[c], 0.f);
        float z1[8]; lin<8,8>(a0, W1, b1, z1);
        float a1[8];
#pragma unroll
        for (int c = 0; c < 8; ++c) a1[c] = fmaxf(z1[c]*sc1[c] + sh1[c], 0.f);
        float z2[16]; lin<16,8>(a1, W2, b2, z2);
#pragma unroll
        for (int o = 0; o < 16; ++o) { acc[o] += z2[o]; acc[16+o] += z2[o]*z2[o]; }
    }
    block_reduce_atomic<32>(acc, statsOut);
}

// ---------------------------------------------------------------------------
// k_fin: fold BN coefficients into linear weights (1 block)
// fold: [0..7]=sc0 [8..15]=sh0 [16..79]=W1f [80..87]=b1f [88..215]=W2f [216..231]=b2f
// ---------------------------------------------------------------------------
__global__ void k_fin(const float* __restrict__ stats,
                      const float* __restrict__ g0, const float* __restrict__ be0,
                      const float* __restrict__ W1, const float* __restrict__ b1,
                      const float* __restrict__ g1, const float* __restrict__ be1,
                      const float* __restrict__ W2, const float* __restrict__ b2,
                      const float* __restrict__ g2, const float* __restrict__ be2,
                      float* __restrict__ fold) {
    __shared__ float sc[32], sh[32];
    const int t = threadIdx.x;
    const float invM = 1.0f / (float)MTOT;
    if (t < 8) {
        const float m = stats[t]*invM, v = stats[8+t]*invM - m*m;
        const float s = frsq(v + 1e-5f) * g0[t];
        sc[t] = s; sh[t] = be0[t] - m*s;
    } else if (t < 16) {
        const int c = t - 8;
        const float m = stats[16+c]*invM, v = stats[24+c]*invM - m*m;
        const float s = frsq(v + 1e-5f) * g1[c];
        sc[t] = s; sh[t] = be1[c] - m*s;
    } else if (t < 32) {
        const int c = t - 16;
        const float m = stats[32+c]*invM, v = stats[48+c]*invM - m*m;
        const float s = frsq(v + 1e-5f) * g2[c];
        sc[t] = s; sh[t] = be2[c] - m*s;
    }
    __syncthreads();
    if (t < 8)   { fold[t] = sc[t]; fold[8+t] = sh[t]; }
    if (t < 64)  fold[16 + t] = sc[8 + (t >> 3)] * W1[t];
    if (t < 8)   fold[80 + t] = sc[8 + t]*b1[t] + sh[8 + t];
    if (t < 128) fold[88 + t] = sc[16 + (t >> 3)] * W2[t];
    if (t < 16)  fold[216 + t] = sc[16 + t]*b2[t] + sh[16 + t];
}

// ---------------------------------------------------------------------------
// k_fused: R6 structure + prefetch prologue (all global loads issued before
// P0's FMA chain so gather latency hides under compute).
// LDS: h1buf [256][40bf16] @0 (20480) -> overlaid by aggL [16][520bf16]
//      h2T [32][264bf16] @20480 (16896);  wBT [16p][272bf16] @37376 (8704)
// ---------------------------------------------------------------------------
__global__ __launch_bounds__(256, 3)
void k_fused(const float* __restrict__ feats,
             const unsigned short* __restrict__ featsbf,
             const int* __restrict__ nei,
             const float* __restrict__ bm1, const float* __restrict__ bm2,
             const float* __restrict__ blin, const float* __restrict__ fold,
             const short* __restrict__ fWm1, const short* __restrict__ fWm2,
             const short* __restrict__ fWlin,
             const unsigned short* __restrict__ z0ws,
             const unsigned short* __restrict__ rmws,
             float* __restrict__ out) {
    __shared__ __align__(16) unsigned char smem[46080];
    const int t    = threadIdx.x;
    const int lane = t & 63;
    const int wv   = t >> 6;
    const int blk  = blockIdx.x;
    const int sbase = blk * 256;
    const int b     = (blk >= 2048) ? 1 : 0;
    const int lrow  = lane & 15;
    const int kq    = lane >> 4;

    // ---- prologue: issue ALL global loads up front ----
    int njv[4];
#pragma unroll
    for (int mt = 0; mt < 4; ++mt)
        njv[mt] = nei[sbase + wv*64 + mt*16 + lrow];

    const uint4 zz = *(const uint4*)(z0ws + (size_t)(sbase + t)*8);

    short8 bW1[3][2];
#pragma unroll
    for (int ks = 0; ks < 3; ++ks)
#pragma unroll
        for (int nt = 0; nt < 2; ++nt)
            bW1[ks][nt] = *(const short8*)(fWm1 + ((ks*2 + nt)*64 + lane)*8);
    short8 bW2[2];
    bW2[0] = *(const short8*)(fWm2 + (0*64 + lane)*8);
    bW2[1] = *(const short8*)(fWm2 + (1*64 + lane)*8);

    short8 fa[4][2];
    uint2  rmv[4];
#pragma unroll
    for (int mt = 0; mt < 4; ++mt) {
        const unsigned short* F = featsbf + ((size_t)(b*NN + njv[mt])) * CC;
        fa[mt][0] = *(const short8*)(F + kq*8);
        fa[mt][1] = *(const short8*)(F + 32 + kq*8);
        rmv[mt]   = *(const uint2*)(rmws + (size_t)(sbase + wv*64 + mt*16 + lrow)*4);
    }

    // ---- P0: z0 -> folded wn chain -> w -> wBT (hides load latency) ----
    {
        const unsigned short* q = (const unsigned short*)&zz;
        float a0[8];
#pragma unroll
        for (int c = 0; c < 8; ++c) a0[c] = fmaxf(bf2f(q[c])*fold[c] + fold[8+c], 0.f);
        float a1[8];
#pragma unroll
        for (int o = 0; o < 8; ++o) {
            float acc = fold[80 + o];
#pragma unroll
            for (int c = 0; c < 8; ++c) acc += a0[c] * fold[16 + o*8 + c];
            a1[o] = fmaxf(acc, 0.f);
        }
        const int p = t >> 4, kk = t & 15;
        unsigned short* WBT = (unsigned short*)(smem + 37376);
#pragma unroll
        for (int o = 0; o < 16; ++o) {
            float acc = fold[216 + o];
#pragma unroll
            for (int c = 0; c < 8; ++c) acc += a1[c] * fold[88 + o*8 + c];
            WBT[p*272 + o*16 + kk] = (unsigned short)f2bf(fmaxf(acc, 0.f));
        }
    }

    // ---- P1: h1 = relu([gfeat,rmiu] @ Wm1^T + bm1) ----
    {
        f32x4 C1[4][2];
#pragma unroll
        for (int mt = 0; mt < 4; ++mt)
#pragma unroll
            for (int nt = 0; nt < 2; ++nt)
                C1[mt][nt] = (f32x4){0.f, 0.f, 0.f, 0.f};

#pragma unroll
        for (int mt = 0; mt < 4; ++mt) {
            C1[mt][0] = mfma16(fa[mt][0], bW1[0][0], C1[mt][0]);
            C1[mt][1] = mfma16(fa[mt][0], bW1[0][1], C1[mt][1]);
            C1[mt][0] = mfma16(fa[mt][1], bW1[1][0], C1[mt][0]);
            C1[mt][1] = mfma16(fa[mt][1], bW1[1][1], C1[mt][1]);
            short8 ar = (short8){0,0,0,0,0,0,0,0};
            if (kq == 0)
                *(uint2*)&ar = rmv[mt];
            C1[mt][0] = mfma16(ar, bW1[2][0], C1[mt][0]);
            C1[mt][1] = mfma16(ar, bW1[2][1], C1[mt][1]);
        }
        unsigned short* H1 = (unsigned short*)smem;
#pragma unroll
        for (int mt = 0; mt < 4; ++mt)
#pragma unroll
            for (int nt = 0; nt < 2; ++nt) {
                const int c = nt*16 + lrow;
                const float bias = bm1[c];
#pragma unroll
                for (int reg = 0; reg < 4; ++reg) {
                    const int s = wv*64 + mt*16 + kq*4 + reg;
                    H1[s*40 + c] = (unsigned short)f2bf(fmaxf(C1[mt][nt][reg] + bias, 0.f));
                }
            }
    }

    // ---- P2: h2 = relu(h1 @ fWm2 + bm2) -> h2T ----
    {
        const unsigned short* H1 = (const unsigned short*)smem;
        f32x4 C2[4][2];
#pragma unroll
        for (int mt = 0; mt < 4; ++mt)
#pragma unroll
            for (int nt = 0; nt < 2; ++nt)
                C2[mt][nt] = (f32x4){0.f, 0.f, 0.f, 0.f};
#pragma unroll
        for (int mt = 0; mt < 4; ++mt) {
            const int s = wv*64 + mt*16 + lrow;
            const short8 a = *(const short8*)(H1 + s*40 + kq*8);
            C2[mt][0] = mfma16(a, bW2[0], C2[mt][0]);
            C2[mt][1] = mfma16(a, bW2[1], C2[mt][1]);
        }
        unsigned short* H2T = (unsigned short*)(smem + 20480);
#pragma unroll
        for (int mt = 0; mt < 4; ++mt)
#pragma unroll
            for (int nt = 0; nt < 2; ++nt) {
                const int c = nt*16 + lrow;
                const float bias = bm2[c];
                const int s0 = wv*64 + mt*16 + kq*4;
                const float r0 = fmaxf(C2[mt][nt][0] + bias, 0.f);
                const float r1 = fmaxf(C2[mt][nt][1] + bias, 0.f);
                const float r2 = fmaxf(C2[mt][nt][2] + bias, 0.f);
                const float r3 = fmaxf(C2[mt][nt][3] + bias, 0.f);
                uint2 pk; pk.x = cvtpk(r0, r1); pk.y = cvtpk(r2, r3);
                *(uint2*)&H2T[c*264 + s0] = pk;
            }
    }

    __syncthreads();   // h1buf reads done before aggL overlays region 0

    // ---- P3: agg[p] = h2_p^T @ w_p -> aggL [p][c*16+j] bf16 ----
    {
        const unsigned short* H2T = (const unsigned short*)(smem + 20480);
        const unsigned short* WBT = (const unsigned short*)(smem + 37376);
        unsigned short* AGG = (unsigned short*)smem;
#pragma unroll
        for (int pi = 0; pi < 4; ++pi) {
            const int p = wv*4 + pi;
            short8 bf = (short8){0,0,0,0,0,0,0,0};
            if (kq < 2)
                bf = *(const short8*)(WBT + p*272 + lrow*16 + kq*8);
#pragma unroll
            for (int ct = 0; ct < 2; ++ct) {
                short8 af = (short8){0,0,0,0,0,0,0,0};
                if (kq < 2) {
                    const int c = ct*16 + lrow;
                    af = *(const short8*)(H2T + c*264 + p*16 + kq*8);
                }
                f32x4 Cg = (f32x4){0.f, 0.f, 0.f, 0.f};
                Cg = mfma16(af, bf, Cg);
#pragma unroll
                for (int reg = 0; reg < 4; ++reg) {
                    const int c = ct*16 + kq*4 + reg;
                    AGG[p*520 + c*16 + lrow] = (unsigned short)f2bf(Cg[reg]);
                }
            }
        }
    }

    __syncthreads();   // aggL complete

    // ---- P4: out = relu(agg @ Wlin^T + blin) + feats ----
    {
        const unsigned short* AGG = (const unsigned short*)smem;
        const int nt = wv;
        f32x4 Co = (f32x4){0.f, 0.f, 0.f, 0.f};
#pragma unroll
        for (int ks = 0; ks < 16; ++ks) {
            const short8 a  = *(const short8*)(AGG + lrow*520 + ks*32 + kq*8);
            const short8 bf = *(const short8*)(fWlin + ((ks*4 + nt)*64 + lane)*8);
            Co = mfma16(a, bf, Co);
        }
        const int o = nt*16 + lrow;
        const float bias = blin[o];
#pragma unroll
        for (int reg = 0; reg < 4; ++reg) {
            const int p = kq*4 + reg;
            const size_t gp = (size_t)blk*16 + p;
            out[gp*CC + o] = fmaxf(Co[reg] + bias, 0.f) + feats[gp*CC + o];
        }
    }
}

// ---------------------------------------------------------------------------
extern "C" void kernel_launch(void* const* d_in, const int* in_sizes, int n_in,
                              void* d_out, int out_size, void* d_ws, size_t ws_size,
                              hipStream_t stream) {
    const float* xyz  = (const float*)d_in[0];
    const float* feats= (const float*)d_in[1];
    const float* xyzn = (const float*)d_in[2];
    const int*   nei  = (const int*)  d_in[3];
    const float* Wm1  = (const float*)d_in[4];
    const float* bm1  = (const float*)d_in[5];
    const float* Wm2  = (const float*)d_in[6];
    const float* bm2  = (const float*)d_in[7];
    const float* W0   = (const float*)d_in[8];
    const float* b0   = (const float*)d_in[9];
    const float* g0   = (const float*)d_in[10];
    const float* be0  = (const float*)d_in[11];
    const float* W1   = (const float*)d_in[12];
    const float* b1   = (const float*)d_in[13];
    const float* g1   = (const float*)d_in[14];
    const float* be1  = (const float*)d_in[15];
    const float* W2   = (const float*)d_in[16];
    const float* b2   = (const float*)d_in[17];
    const float* g2   = (const float*)d_in[18];
    const float* be2  = (const float*)d_in[19];
    const float* Wlin = (const float*)d_in[20];
    const float* blin = (const float*)d_in[21];

    float* out = (float*)d_out;
    char*  ws  = (char*)d_ws;

    float*          stats   = (float*)ws;                        // 256 B @ 0
    float*          fold    = (float*)(ws + 256);                // 232 f
    short*          fWm1    = (short*)(ws + 2048);               // 6144 B
    short*          fWm2    = (short*)(ws + 8192);               // 2048 B
    short*          fWlin   = (short*)(ws + 16384);              // 64 KB
    unsigned short* featsbf = (unsigned short*)(ws + 131072);    // 8 MB
    unsigned short* z0ws    = (unsigned short*)(ws + 8519680);   // 16 MB
    unsigned short* rmws    = (unsigned short*)(ws + 25296896);  // 8 MB

    hipMemsetAsync(stats, 0, 256, stream);

    kA<<<1024, 256, 0, stream>>>(xyz, xyzn, nei, W0, b0, Wm1, Wm2, Wlin,
                                 feats, z0ws, rmws, fWm1, fWm2, fWlin,
                                 featsbf, stats);
    kB<<<1024, 256, 0, stream>>>(z0ws, W1, b1, g0, be0, stats, stats + 16);
    kC<<<1024, 256, 0, stream>>>(z0ws, W1, b1, W2, b2, g0, be0, g1, be1,
                                 stats, stats + 32);
    k_fin<<<1, 256, 0, stream>>>(stats, g0, be0, W1, b1, g1, be1,
                                 W2, b2, g2, be2, fold);
    k_fused<<<4096, 256, 0, stream>>>(feats, featsbf, nei, bm1, bm2, blin,
                                      fold, fWm1, fWm2, fWlin, z0ws, rmws, out);
}